// Round 6
// baseline (317.480 us; speedup 1.0000x reference)
//
#include <hip/hip_runtime.h>
#include <hip/hip_bf16.h>
#include <math.h>

// Problem constants (match reference)
#define Bg 16
#define Nn 2048
#define Ee (1<<20)
#define NT (Bg*Nn)
#define INC 256
#define DIMd 128
#define OUTC 6
#define ENCH 100
#define NATOMS 20
#define BINCAP 3072   // per-bin edge capacity: mean 2048, sigma~44 -> +23 sigma

typedef __attribute__((ext_vector_type(8))) short bf16x8;
typedef __attribute__((ext_vector_type(4))) float f32x4;

__device__ __forceinline__ float gelu_f(float x){
    return 0.5f*x*(1.0f+erff(x*0.70710678118654752440f));
}
__device__ __forceinline__ unsigned short f2b(float f){
    __hip_bfloat16 h = __float2bfloat16(f);
    return *(unsigned short*)&h;
}
__device__ __forceinline__ float b2f(unsigned short u){
    unsigned v = ((unsigned)u)<<16;
    return __uint_as_float(v);
}
// split fp32 into bf16 hi + bf16 lo (v ~= hi + lo, dropped residual ~2^-18 rel)
__device__ __forceinline__ void splitf(float v, unsigned short& hi, unsigned short& lo){
    unsigned short h = f2b(v);
    hi = h; lo = f2b(v - b2f(h));
}

// ---- Kernel 1: prep0 = BN stats (blocks 0..255) + weight split (256..319) --
__global__ __launch_bounds__(256) void prep0_k(const float* __restrict__ x,
    float* __restrict__ stats, const float* __restrict__ W1,
    const float* __restrict__ W2, const float* __restrict__ Wm,
    const float* __restrict__ A1, short* __restrict__ w1th, short* __restrict__ w1tl,
    short* __restrict__ w2th, short* __restrict__ w2tl,
    short* __restrict__ wmth, short* __restrict__ wmtl,
    short* __restrict__ a1th, short* __restrict__ a1tl)
{
    int bx = blockIdx.x, tid = threadIdx.x;
    if(bx < 256){
        int c = tid;
        int r0 = bx * 128;
        const float* p = x + (size_t)r0*INC + c;
        float s = 0.f, s2 = 0.f;
        #pragma unroll 8
        for(int r=0;r<128;r++){ float v = p[(size_t)r*INC]; s += v; s2 += v*v; }
        atomicAdd(&stats[c], s);
        atomicAdd(&stats[INC+c], s2);
    } else {
        int gid = (bx-256)*256 + tid;             // 64 blocks -> 16384 threads
        unsigned short hi, lo;
        for(int l=gid;l<65536;l+=16384){ int n=l>>8,k=l&255;
            splitf(W1[(size_t)k*256+n],hi,lo); w1th[l]=(short)hi; w1tl[l]=(short)lo; }
        for(int l=gid;l<32768;l+=16384){ int n=l>>8,k=l&255;
            splitf(W2[(size_t)k*128+n],hi,lo); w2th[l]=(short)hi; w2tl[l]=(short)lo; }
        for(int l=gid;l<16384;l+=16384){ int n=l>>7,k=l&127;
            splitf(Wm[(size_t)k*128+n],hi,lo); wmth[l]=(short)hi; wmtl[l]=(short)lo; }
        for(int l=gid;l<16384;l+=16384){ int n=l>>7,k=l&127;
            float v=(n<ENCH)? A1[(size_t)k*ENCH+n] : 0.f;
            splitf(v,hi,lo); a1th[l]=(short)hi; a1tl[l]=(short)lo; }
    }
}

// ---- Kernel 2: FUSED h1=gelu(BN(x)@W1+b1) -> h2=gelu(h1@W2+b2) -> argmax ---
// M=32 rows/block, grid 1024 (~3 blocks/CU resident via 47KB LDS).
// h1 never leaves the block: G2 consumes it chunk-by-chunk from LDS.
// Blocks 0..255 append the edge bucket-scatter tail (runs in dispatch round 1,
// imbalance absorbed by rounds 2-4).
__global__ __launch_bounds__(256) void gemm123_k(const float* __restrict__ x,
    const float* __restrict__ stats, const float* __restrict__ gamma,
    const float* __restrict__ beta, const short* __restrict__ w1th,
    const short* __restrict__ w1tl, const float* __restrict__ b1,
    const short* __restrict__ w2th, const short* __restrict__ w2tl,
    const float* __restrict__ b2, const float* __restrict__ W3,
    const float* __restrict__ b3, int* __restrict__ ids,
    const int* __restrict__ ei, unsigned* __restrict__ ecnt,
    unsigned* __restrict__ earena)
{
    __shared__ float sc[256], sh[256];
    __shared__ short sAh[32*40], sAl[32*40];   // G1 A-tiles; G2 h1-chunk planes
    __shared__ short sBh[256*40], sBl[256*40]; // G1 W1; G2 W2[128*40]; logits h2s/lgs/w3s
    int tid = threadIdx.x;
    {
        float mu  = stats[tid]*(1.0f/NT);
        float var = stats[256+tid]*(1.0f/NT) - mu*mu;
        float s = gamma[tid]/sqrtf(var + 1e-5f);
        sc[tid] = s; sh[tid] = beta[tid] - mu*s;
    }
    int row0 = blockIdx.x*32;
    int lane = tid&63, w = tid>>6;
    int ln = lane&15, quad = lane>>4;
    int mt = (w&1)*16, nb1 = (w>>1)*128, nb2 = (w>>1)*64;

    // --- G1: h1 acc, 3-term split MFMA, K=256 -------------------------------
    f32x4 acc[8];
    #pragma unroll
    for(int j=0;j<8;j++) acc[j] = (f32x4){0.f,0.f,0.f,0.f};
    float bias1[8];
    #pragma unroll
    for(int tn=0;tn<8;tn++) bias1[tn] = b1[nb1 + tn*16 + ln];

    int ar = tid>>3, akq = (tid&7)*4;                 // A-staging coords
    float4 xa = *(const float4*)&x[(size_t)(row0+ar)*256 + akq];
    bf16x8 wb[8];
    #pragma unroll
    for(int i=0;i<8;i++){ int id=tid+i*256; int plane=id>>10,cid=id&1023;
        int r=cid>>2,c=cid&3;
        wb[i] = *(const bf16x8*)((plane? w1tl:w1th) + (size_t)r*256 + c*8); }
    __syncthreads();
    for(int k0=0;k0<256;k0+=32){
        {                                             // A: BN(x) split -> LDS
            int k = k0+akq;
            float v0 = xa.x*sc[k]+sh[k],     v1 = xa.y*sc[k+1]+sh[k+1];
            float v2 = xa.z*sc[k+2]+sh[k+2], v3 = xa.w*sc[k+3]+sh[k+3];
            ushort4 hi, lo;
            splitf(v0,hi.x,lo.x); splitf(v1,hi.y,lo.y);
            splitf(v2,hi.z,lo.z); splitf(v3,hi.w,lo.w);
            *(ushort4*)&sAh[ar*40+akq] = hi;
            *(ushort4*)&sAl[ar*40+akq] = lo;
        }
        #pragma unroll
        for(int i=0;i<8;i++){                         // B regs -> LDS
            int id = tid + i*256; int plane = id>>10, cid = id&1023;
            int r = cid>>2, c = cid&3;
            *(bf16x8*)((plane? sBl : sBh) + r*40 + c*8) = wb[i];
        }
        __syncthreads();
        if(k0 < 224){                                 // prefetch next K-tile
            xa = *(const float4*)&x[(size_t)(row0+ar)*256 + k0+32+akq];
            #pragma unroll
            for(int i=0;i<8;i++){ int id=tid+i*256; int plane=id>>10,cid=id&1023;
                int r=cid>>2,c=cid&3;
                wb[i] = *(const bf16x8*)((plane? w1tl:w1th) + (size_t)r*256 + k0+32 + c*8); }
        }
        bf16x8 ah = *(const bf16x8*)&sAh[(mt+ln)*40 + quad*8];
        bf16x8 al = *(const bf16x8*)&sAl[(mt+ln)*40 + quad*8];
        #pragma unroll
        for(int tn=0;tn<8;tn++){
            bf16x8 bh = *(const bf16x8*)&sBh[(nb1+tn*16+ln)*40 + quad*8];
            bf16x8 bl = *(const bf16x8*)&sBl[(nb1+tn*16+ln)*40 + quad*8];
            acc[tn] = __builtin_amdgcn_mfma_f32_16x16x32_bf16(al, bh, acc[tn], 0,0,0);
            acc[tn] = __builtin_amdgcn_mfma_f32_16x16x32_bf16(ah, bl, acc[tn], 0,0,0);
            acc[tn] = __builtin_amdgcn_mfma_f32_16x16x32_bf16(ah, bh, acc[tn], 0,0,0);
        }
        __syncthreads();
    }

    // --- G2: h2 += split(h1_chunk) @ W2_chunk, 8 chunks of k=32 -------------
    f32x4 acc2[4];
    #pragma unroll
    for(int j=0;j<4;j++) acc2[j] = (f32x4){0.f,0.f,0.f,0.f};
    bf16x8 wb2[4];
    #pragma unroll
    for(int i=0;i<4;i++){ int id=tid+i*256; int plane=id>>9,cid=id&511;
        int r=cid>>2,c=cid&3;
        wb2[i] = *(const bf16x8*)((plane? w2tl:w2th) + (size_t)r*256 + c*8); }
    #pragma unroll
    for(int cc=0;cc<8;cc++){
        if((w>>1) == (cc>>2)){                        // write h1 chunk (2 waves)
            int cl = cc&3;
            #pragma unroll
            for(int t=0;t<2;t++){
                int tn = 2*cl + t;
                #pragma unroll
                for(int r=0;r<4;r++){
                    int row = mt + quad*4 + r;
                    float hv = gelu_f(acc[tn][r] + bias1[tn]);
                    unsigned short hi, lo;
                    splitf(hv, hi, lo);
                    sAh[row*40 + t*16 + ln] = (short)hi;
                    sAl[row*40 + t*16 + ln] = (short)lo;
                }
            }
        }
        #pragma unroll
        for(int i=0;i<4;i++){                         // W2 tile regs -> LDS
            int id = tid + i*256; int plane = id>>9, cid = id&511;
            int r = cid>>2, c = cid&3;
            *(bf16x8*)((plane? sBl : sBh) + r*40 + c*8) = wb2[i];
        }
        __syncthreads();
        if(cc < 7){                                   // prefetch next W2 tile
            #pragma unroll
            for(int i=0;i<4;i++){ int id=tid+i*256; int plane=id>>9,cid=id&511;
                int r=cid>>2,c=cid&3;
                wb2[i] = *(const bf16x8*)((plane? w2tl:w2th)
                          + (size_t)r*256 + (cc+1)*32 + c*8); }
        }
        bf16x8 ah = *(const bf16x8*)&sAh[(mt+ln)*40 + quad*8];
        bf16x8 al = *(const bf16x8*)&sAl[(mt+ln)*40 + quad*8];
        #pragma unroll
        for(int tn=0;tn<4;tn++){
            bf16x8 bh = *(const bf16x8*)&sBh[(nb2+tn*16+ln)*40 + quad*8];
            bf16x8 bl = *(const bf16x8*)&sBl[(nb2+tn*16+ln)*40 + quad*8];
            acc2[tn] = __builtin_amdgcn_mfma_f32_16x16x32_bf16(al, bh, acc2[tn], 0,0,0);
            acc2[tn] = __builtin_amdgcn_mfma_f32_16x16x32_bf16(ah, bl, acc2[tn], 0,0,0);
            acc2[tn] = __builtin_amdgcn_mfma_f32_16x16x32_bf16(ah, bh, acc2[tn], 0,0,0);
        }
        __syncthreads();
    }

    // --- logits = h2@W3+b3; argmax -----------------------------------------
    float* h2s = (float*)sBh;                         // [32][132] = 16896 B
    float* lgs = (float*)sBl;                         // [32][20]  = 2560 B
    float* w3s = ((float*)sBl) + 640;                 // 2560 f32  = 10240 B
    #pragma unroll
    for(int tn=0;tn<4;tn++){
        int col = nb2 + tn*16 + ln;
        float bias = b2[col];
        #pragma unroll
        for(int r=0;r<4;r++){
            int row = mt + quad*4 + r;
            h2s[row*132 + col] = gelu_f(acc2[tn][r] + bias);
        }
    }
    for(int l=tid;l<2560;l+=256) w3s[l] = W3[l];
    __syncthreads();
    if(tid<128){
        int n = tid>>2, q = tid&3;
        float lg[5] = {};
        #pragma unroll 4
        for(int k=0;k<128;k++){
            float h = h2s[n*132+k];
            #pragma unroll
            for(int a=0;a<5;a++) lg[a] += h*w3s[k*20 + q*5 + a];
        }
        #pragma unroll
        for(int a=0;a<5;a++) lgs[n*20 + q*5 + a] = lg[a] + b3[q*5+a];
    }
    __syncthreads();
    if(tid<32){                                       // numpy argmax: first max
        float best = lgs[tid*20]; int bi = 0;
        #pragma unroll
        for(int a=1;a<20;a++){ float v2 = lgs[tid*20+a]; if(v2>best){best=v2;bi=a;} }
        ids[row0+tid] = bi;
    }

    // ---- edge bucket-scatter tail (blocks 0..255; 4096 edges each) --------
    if(blockIdx.x < 256){
        __syncthreads();                     // sA dead -> reuse as counters
        unsigned* lcnt  = (unsigned*)sAh;    // 512 u32
        unsigned* gbase = (unsigned*)sAl;    // 512 u32
        for(int l=tid; l<512; l+=256) lcnt[l] = 0;
        __syncthreads();
        int ebase = blockIdx.x * 4096;
        #pragma unroll 4
        for(int i=0;i<16;i++){
            int e = ebase + i*256 + tid;
            int s = ei[e], d = ei[Ee+e];
            if((s>>11)==(d>>11)) atomicAdd(&lcnt[s>>6], 1u);
        }
        __syncthreads();
        for(int l=tid; l<512; l+=256){
            unsigned c = lcnt[l];
            gbase[l] = c ? atomicAdd(&ecnt[l], c) : 0u;
            lcnt[l] = 0;
        }
        __syncthreads();
        #pragma unroll 4
        for(int i=0;i<16;i++){
            int e = ebase + i*256 + tid;
            int s = ei[e], d = ei[Ee+e];
            if((s>>11)==(d>>11)){
                int bin = s>>6;
                unsigned r = atomicAdd(&lcnt[bin], 1u);
                unsigned pos = gbase[bin] + r;
                if(pos < BINCAP)
                    earena[(size_t)bin*BINCAP + pos] =
                        ((unsigned)(s&63)<<11) | (unsigned)(d&2047);
            }
        }
    }
}

// ---- Kernel 3: LDS adjacency rebuild + aggregation + hout GEMM + heads -----
// grid 512 (64 nodes each = bucket blockIdx). 4 waves.
__global__ __launch_bounds__(256) void msg3_k(
    const int* __restrict__ ids, const unsigned* __restrict__ ecnt,
    const unsigned* __restrict__ earena, const float* __restrict__ embed,
    const short* __restrict__ wmth, const short* __restrict__ wmtl,
    const float* __restrict__ b_msg, const float* __restrict__ w_coor,
    const short* __restrict__ a1th, const short* __restrict__ a1tl,
    const float* __restrict__ a1v, const float* __restrict__ A2,
    const float* __restrict__ a2v, const float* __restrict__ dalpha,
    const float* __restrict__ dw, const float* __restrict__ db,
    const float* __restrict__ coords, float* __restrict__ out_ang,
    float* __restrict__ out_z, float* __restrict__ out_co)
{
    __shared__ unsigned short v_bf[64*136];    // v bf16 (row pad 136)
    __shared__ unsigned short houts[64*136];   // hout bf16; later t1s [64][104]
    // arena phase 0/1: lmask u32[4096] | ind u32[1280] | sid u8[2048] | emb f32[2560]
    // GEMM phases:     sBh[10240 B] | sBl[10240 B] (overlays lmask+ind)
    __shared__ __align__(16) unsigned char arena[33792];
    __shared__ float s_bm[128], s_wc[384], s_A2[624], s_a1[104];
    __shared__ float s_dyt[16], s_a2[8];

    unsigned*       lmask = (unsigned*)arena;
    unsigned*       ind   = (unsigned*)(arena + 16384);
    unsigned char*  sid   = arena + 21504;
    float*          emb   = (float*)(arena + 23552);
    short*          sBh   = (short*)arena;
    short*          sBl   = (short*)(arena + 10240);

    int tid = threadIdx.x;
    int bin = blockIdx.x;
    int row0 = bin*64;
    int g = blockIdx.x>>5, tile = blockIdx.x&31;
    int lane = tid&63, w = tid>>6;
    int ln = lane&15, quad = lane>>4;
    int m0w = (w&1)*32, n0w = (w>>1)*64;

    // --- phase 0: constants + emb + sid + zero lmask ------------------------
    for(int l=tid;l<NATOMS*128;l+=256) emb[l] = embed[l];
    #pragma unroll
    for(int i=0;i<8;i++){ int j = tid + i*256; sid[j] = (unsigned char)ids[g*Nn + j]; }
    #pragma unroll
    for(int i=0;i<16;i++) lmask[tid + i*256] = 0;
    if(tid<128) s_bm[tid] = b_msg[tid];
    if(tid<104) s_a1[tid] = (tid<ENCH) ? a1v[tid] : 0.f;
    for(int l=tid;l<384;l+=256) s_wc[l] = w_coor[l];
    for(int l=tid;l<624;l+=256) s_A2[l] = (l<600) ? A2[l] : 0.f;
    if(tid==0)  s_dyt[0] = dalpha[0];
    if(tid<6){ s_dyt[1+tid] = dw[tid]; s_dyt[8+tid] = db[tid]; }
    if(tid<8)  s_a2[tid] = (tid<6) ? a2v[tid] : 0.f;
    int nb = min((int)ecnt[bin], BINCAP);
    __syncthreads();

    // --- phase 1: ballot indicator bitmasks + LDS adjacency build -----------
    for(int wp=w; wp<32; wp+=4){
        int a = sid[wp*64 + lane];
        #pragma unroll
        for(int atom=0; atom<NATOMS; atom++){
            unsigned long long bm = __ballot(a==atom);
            if(lane<2) ind[atom*64 + wp*2 + lane] = (unsigned)(bm >> (32*lane));
        }
    }
    for(int i=tid; i<nb; i+=256){
        unsigned wv = earena[(size_t)bin*BINCAP + i];
        int sl = wv>>11, dl = wv & 2047;
        atomicOr(&lmask[sl*64 + (dl>>5)], 1u<<(dl&31));
    }
    __syncthreads();

    // --- phase 2: per-node counts popcount(lmask & ind), 4-lane split -------
    int node = tid>>2, p = tid&3;
    unsigned mw[16];
    {
        const unsigned* mrow = &lmask[node*64 + p*16];
        *(uint4*)&mw[0]  = *(const uint4*)&mrow[0];
        *(uint4*)&mw[4]  = *(const uint4*)&mrow[4];
        *(uint4*)&mw[8]  = *(const uint4*)&mrow[8];
        *(uint4*)&mw[12] = *(const uint4*)&mrow[12];
    }
    int degi = 0;
    #pragma unroll
    for(int w2=0;w2<16;w2++) degi += __popc(mw[w2]);
    float cnt[NATOMS];
    #pragma unroll
    for(int a=0;a<NATOMS;a++){
        int c = 0;
        const unsigned* ia = &ind[a*64 + p*16];
        #pragma unroll
        for(int w2=0;w2<16;w2++) c += __popc(mw[w2] & ia[w2]);
        cnt[a] = (float)c;
    }
    #pragma unroll
    for(int a=0;a<NATOMS;a++){
        cnt[a] += __shfl_xor(cnt[a],1,64);
        cnt[a] += __shfl_xor(cnt[a],2,64);
    }
    float deg = (float)degi;
    deg += __shfl_xor(deg,1,64);
    deg += __shfl_xor(deg,2,64);

    // --- v = emb[own] + (sum_a cnt_a emb_a)/max(deg,1) -> LDS bf16 ----------
    {
        float inv = 1.0f / fmaxf(deg, 1.0f);
        int oid = sid[tile*64 + node];
        int d0 = p*32;
        float vv[32];
        #pragma unroll
        for(int d=0;d<32;d++) vv[d]=0.f;
        #pragma unroll
        for(int a=0;a<NATOMS;a++){
            float ca = cnt[a];
            const float* ea = &emb[a*128 + d0];
            #pragma unroll
            for(int d=0;d<32;d+=4){
                float4 e = *(const float4*)&ea[d];
                vv[d]+=ca*e.x; vv[d+1]+=ca*e.y; vv[d+2]+=ca*e.z; vv[d+3]+=ca*e.w;
            }
        }
        const float* eo = &emb[oid*128 + d0];
        unsigned short* dst = &v_bf[node*136 + d0];
        #pragma unroll
        for(int d=0;d<32;d+=4){
            float4 e = *(const float4*)&eo[d];
            ushort4 o;
            o.x = f2b(e.x + vv[d]*inv);
            o.y = f2b(e.y + vv[d+1]*inv);
            o.z = f2b(e.z + vv[d+2]*inv);
            o.w = f2b(e.w + vv[d+3]*inv);
            *(ushort4*)&dst[d] = o;
        }
    }
    __syncthreads();     // v complete; lmask/ind/sid/emb dead -> arena = sB

    // ---- hout = gelu(v @ W_msg + b), 2-term W split, A direct from v_bf ----
    f32x4 acc[2][4];
    #pragma unroll
    for(int i=0;i<2;i++)
        #pragma unroll
        for(int j=0;j<4;j++) acc[i][j] = (f32x4){0.f,0.f,0.f,0.f};
    for(int k0=0;k0<128;k0+=32){
        #pragma unroll
        for(int i=0;i<4;i++){                           // B: Wmsg_t [128][32]
            int id = tid + i*256; int plane = id>>9, cid = id&511;
            int r = cid>>2, c = cid&3;
            const short* src = (plane? wmtl : wmth) + (size_t)r*128 + k0 + c*8;
            short* dst = (plane? sBl : sBh) + r*40 + c*8;
            *(bf16x8*)dst = *(const bf16x8*)src;
        }
        __syncthreads();
        bf16x8 av[2];
        #pragma unroll
        for(int tm=0;tm<2;tm++)
            av[tm] = *(const bf16x8*)&v_bf[(m0w+tm*16+ln)*136 + k0 + quad*8];
        #pragma unroll
        for(int tn=0;tn<4;tn++){
            bf16x8 bh = *(const bf16x8*)&sBh[(n0w+tn*16+ln)*40 + quad*8];
            bf16x8 bl = *(const bf16x8*)&sBl[(n0w+tn*16+ln)*40 + quad*8];
            #pragma unroll
            for(int tm=0;tm<2;tm++){
                acc[tm][tn] = __builtin_amdgcn_mfma_f32_16x16x32_bf16(av[tm], bl, acc[tm][tn], 0,0,0);
                acc[tm][tn] = __builtin_amdgcn_mfma_f32_16x16x32_bf16(av[tm], bh, acc[tm][tn], 0,0,0);
            }
        }
        __syncthreads();
    }
    // epilogue: z fp32 + hout bf16 to LDS
    #pragma unroll
    for(int tn=0;tn<4;tn++){
        int col = n0w + tn*16 + ln;
        float bias = s_bm[col];
        #pragma unroll
        for(int tm=0;tm<2;tm++){
            int mb2 = m0w + tm*16 + quad*4;
            #pragma unroll
            for(int r=0;r<4;r++){
                float hv = gelu_f(acc[tm][tn][r] + bias);
                out_z[(size_t)(row0+mb2+r)*128 + col] = hv;
                houts[(mb2+r)*136 + col] = f2b(hv);
            }
        }
    }
    __syncthreads();

    // ---- coors: 4-lane k-split dot with w_coor -----------------------------
    {
        float d0=0.f, d1=0.f, d2=0.f;
        int kb = p*32;
        #pragma unroll
        for(int k=0;k<32;k+=4){
            ushort4 hv = *(const ushort4*)&houts[node*136 + kb + k];
            float h0=b2f(hv.x),h1=b2f(hv.y),h2=b2f(hv.z),h3=b2f(hv.w);
            const float* wc = &s_wc[(kb+k)*3];
            d0 += h0*wc[0]+h1*wc[3]+h2*wc[6]+h3*wc[9];
            d1 += h0*wc[1]+h1*wc[4]+h2*wc[7]+h3*wc[10];
            d2 += h0*wc[2]+h1*wc[5]+h2*wc[8]+h3*wc[11];
        }
        d0 += __shfl_xor(d0,1,64); d0 += __shfl_xor(d0,2,64);
        d1 += __shfl_xor(d1,1,64); d1 += __shfl_xor(d1,2,64);
        d2 += __shfl_xor(d2,1,64); d2 += __shfl_xor(d2,2,64);
        if(p==0){
            size_t o = (size_t)(row0+node)*3;
            out_co[o+0] = coords[o+0] + tanhf(d0);
            out_co[o+1] = coords[o+1] + tanhf(d1);
            out_co[o+2] = coords[o+2] + tanhf(d2);
        }
    }

    // ---- t1 = gelu(hout @ A1 + a1), 2-term split, N=128 (cols>=100 zero) ---
    f32x4 acc2[2][4];
    #pragma unroll
    for(int i=0;i<2;i++)
        #pragma unroll
        for(int j=0;j<4;j++) acc2[i][j] = (f32x4){0.f,0.f,0.f,0.f};
    for(int k0=0;k0<128;k0+=32){
        __syncthreads();                    // protect sB reuse across iters
        #pragma unroll
        for(int i=0;i<4;i++){
            int id = tid + i*256; int plane = id>>9, cid = id&511;
            int r = cid>>2, c = cid&3;
            const short* src = (plane? a1tl : a1th) + (size_t)r*128 + k0 + c*8;
            short* dst = (plane? sBl : sBh) + r*40 + c*8;
            *(bf16x8*)dst = *(const bf16x8*)src;
        }
        __syncthreads();
        bf16x8 ah[2];
        #pragma unroll
        for(int tm=0;tm<2;tm++)
            ah[tm] = *(const bf16x8*)&houts[(m0w+tm*16+ln)*136 + k0 + quad*8];
        #pragma unroll
        for(int tn=0;tn<4;tn++){
            bf16x8 bh = *(const bf16x8*)&sBh[(n0w+tn*16+ln)*40 + quad*8];
            bf16x8 bl = *(const bf16x8*)&sBl[(n0w+tn*16+ln)*40 + quad*8];
            #pragma unroll
            for(int tm=0;tm<2;tm++){
                acc2[tm][tn] = __builtin_amdgcn_mfma_f32_16x16x32_bf16(ah[tm], bl, acc2[tm][tn], 0,0,0);
                acc2[tm][tn] = __builtin_amdgcn_mfma_f32_16x16x32_bf16(ah[tm], bh, acc2[tm][tn], 0,0,0);
            }
        }
    }
    __syncthreads();                        // houts reads done -> reuse as t1s
    unsigned short* t1s = houts;            // [64][104]
    #pragma unroll
    for(int tn=0;tn<4;tn++){
        int col = n0w + tn*16 + ln;
        if(col < 104){
            float bias = s_a1[col];
            #pragma unroll
            for(int tm=0;tm<2;tm++){
                int mb2 = m0w + tm*16 + quad*4;
                #pragma unroll
                for(int r=0;r<4;r++)
                    t1s[(mb2+r)*104 + col] = f2b(gelu_f(acc2[tm][tn][r] + bias));
            }
        }
    }
    __syncthreads();

    // ---- t2 = gelu(t1@A2+a2); DyT; angles ----------------------------------
    {
        int g0 = (p<2) ? p*7 : 14+(p-2)*6;
        int gcount = (p<2) ? 7 : 6;
        float s[6] = {0.f,0.f,0.f,0.f,0.f,0.f};
        for(int gg=0; gg<gcount; gg++){
            int kb = (g0+gg)*4;
            ushort4 tv = *(const ushort4*)&t1s[node*104 + kb];
            float u0=b2f(tv.x), u1=b2f(tv.y), u2=b2f(tv.z), u3=b2f(tv.w);
            #pragma unroll
            for(int j=0;j<6;j++)
                s[j] += u0*s_A2[kb*6+j] + u1*s_A2[(kb+1)*6+j]
                      + u2*s_A2[(kb+2)*6+j] + u3*s_A2[(kb+3)*6+j];
        }
        #pragma unroll
        for(int j=0;j<6;j++){ s[j]+=__shfl_xor(s[j],1,64); s[j]+=__shfl_xor(s[j],2,64); }
        if(p<2){
            size_t o = (size_t)(row0+node)*6 + p*3;
            #pragma unroll
            for(int jj=0;jj<3;jj++){
                int j = p*3+jj;
                float t2v = gelu_f(s[j] + s_a2[j]);
                float uu = tanhf(s_dyt[0]*t2v)*s_dyt[1+j] + s_dyt[8+j];
                out_ang[o+jj] = tanhf(uu);
            }
        }
    }
}

// ---------------------------------------------------------------------------
extern "C" void kernel_launch(void* const* d_in, const int* in_sizes, int n_in,
                              void* d_out, int out_size, void* d_ws, size_t ws_size,
                              hipStream_t stream) {
    const float* x      = (const float*)d_in[0];
    const float* coords = (const float*)d_in[1];
    const int*   ei     = (const int*)d_in[2];
    const float* gamma  = (const float*)d_in[4];
    const float* beta   = (const float*)d_in[5];
    const float* W1     = (const float*)d_in[6];
    const float* b1     = (const float*)d_in[7];
    const float* W2     = (const float*)d_in[8];
    const float* b2     = (const float*)d_in[9];
    const float* W3     = (const float*)d_in[10];
    const float* b3     = (const float*)d_in[11];
    const float* embed  = (const float*)d_in[12];
    const float* W_msg  = (const float*)d_in[13];
    const float* b_msg  = (const float*)d_in[14];
    const float* w_coor = (const float*)d_in[15];
    const float* A1     = (const float*)d_in[16];
    const float* a1v    = (const float*)d_in[17];
    const float* A2     = (const float*)d_in[18];
    const float* a2v    = (const float*)d_in[19];
    const float* dalpha = (const float*)d_in[20];
    const float* dw     = (const float*)d_in[21];
    const float* db     = (const float*)d_in[22];

    // ws layout (~7.3 MB peak):
    //  0      : ids   (128 KB)
    //  128K   : stats (2 KB) + ecnt (2 KB)   <- one 4 KB memset
    //  256K   : weight planes (512 KB)
    //  1M     : earena u32[512*3072] (6 MB)
    char* ws = (char*)d_ws;
    int*      ids   = (int*)ws;
    float*    stats = (float*)(ws + 131072);
    unsigned* ecnt  = (unsigned*)(ws + 131072 + 2048);
    short*    w1th  = (short*)(ws + 262144);
    short*    w1tl  = w1th + 65536;
    short*    w2th  = w1tl + 65536;
    short*    w2tl  = w2th + 32768;
    short*    wmth  = w2tl + 32768;
    short*    wmtl  = wmth + 16384;
    short*    a1th  = wmtl + 16384;
    short*    a1tl  = a1th + 16384;
    unsigned* earena = (unsigned*)(ws + (1<<20));

    float* out_ang = (float*)d_out;
    float* out_z   = out_ang + (size_t)NT*OUTC;
    float* out_co  = out_z   + (size_t)NT*DIMd;

    hipMemsetAsync(stats, 0, 4096, stream);      // stats + ecnt
    prep0_k<<<320, 256, 0, stream>>>(x, stats, W1, W2, W_msg, A1,
        w1th, w1tl, w2th, w2tl, wmth, wmtl, a1th, a1tl);
    gemm123_k<<<1024, 256, 0, stream>>>(x, stats, gamma, beta, w1th, w1tl, b1,
        w2th, w2tl, b2, W3, b3, ids, ei, ecnt, earena);
    msg3_k<<<512, 256, 0, stream>>>(ids, ecnt, earena, embed, wmth, wmtl, b_msg,
        w_coor, a1th, a1tl, a1v, A2, a2v, dalpha, dw, db, coords,
        out_ang, out_z, out_co);
}

// Round 7
// 268.107 us; speedup vs baseline: 1.1842x; 1.1842x over previous
//
#include <hip/hip_runtime.h>
#include <hip/hip_bf16.h>
#include <math.h>

// Problem constants (match reference)
#define Bg 16
#define Nn 2048
#define Ee (1<<20)
#define NT (Bg*Nn)
#define INC 256
#define DIMd 128
#define OUTC 6
#define ENCH 100
#define NATOMS 20
#define BINCAP 3072   // per-bin edge capacity: mean 2048, sigma~44 -> +23 sigma

typedef __attribute__((ext_vector_type(8))) short bf16x8;
typedef __attribute__((ext_vector_type(4))) float f32x4;

__device__ __forceinline__ float gelu_f(float x){
    return 0.5f*x*(1.0f+erff(x*0.70710678118654752440f));
}
__device__ __forceinline__ unsigned short f2b(float f){
    __hip_bfloat16 h = __float2bfloat16(f);
    return *(unsigned short*)&h;
}
__device__ __forceinline__ float b2f(unsigned short u){
    unsigned v = ((unsigned)u)<<16;
    return __uint_as_float(v);
}
// split fp32 into bf16 hi + bf16 lo (v ~= hi + lo, dropped residual ~2^-18 rel)
__device__ __forceinline__ void splitf(float v, unsigned short& hi, unsigned short& lo){
    unsigned short h = f2b(v);
    hi = h; lo = f2b(v - b2f(h));
}

// ---- Kernel 1: prep0 = BN stats (blocks 0..255) + weight split (256..319) --
__global__ __launch_bounds__(256) void prep0_k(const float* __restrict__ x,
    float* __restrict__ stats, const float* __restrict__ W1,
    const float* __restrict__ W2, const float* __restrict__ Wm,
    const float* __restrict__ A1, short* __restrict__ w1th, short* __restrict__ w1tl,
    short* __restrict__ w2th, short* __restrict__ w2tl,
    short* __restrict__ wmth, short* __restrict__ wmtl,
    short* __restrict__ a1th, short* __restrict__ a1tl)
{
    int bx = blockIdx.x, tid = threadIdx.x;
    if(bx < 256){
        int c = tid;
        int r0 = bx * 128;
        const float* p = x + (size_t)r0*INC + c;
        float s = 0.f, s2 = 0.f;
        #pragma unroll 8
        for(int r=0;r<128;r++){ float v = p[(size_t)r*INC]; s += v; s2 += v*v; }
        atomicAdd(&stats[c], s);
        atomicAdd(&stats[INC+c], s2);
    } else {
        int gid = (bx-256)*256 + tid;             // 64 blocks -> 16384 threads
        unsigned short hi, lo;
        for(int l=gid;l<65536;l+=16384){ int n=l>>8,k=l&255;
            splitf(W1[(size_t)k*256+n],hi,lo); w1th[l]=(short)hi; w1tl[l]=(short)lo; }
        for(int l=gid;l<32768;l+=16384){ int n=l>>8,k=l&255;
            splitf(W2[(size_t)k*128+n],hi,lo); w2th[l]=(short)hi; w2tl[l]=(short)lo; }
        for(int l=gid;l<16384;l+=16384){ int n=l>>7,k=l&127;
            splitf(Wm[(size_t)k*128+n],hi,lo); wmth[l]=(short)hi; wmtl[l]=(short)lo; }
        for(int l=gid;l<16384;l+=16384){ int n=l>>7,k=l&127;
            float v=(n<ENCH)? A1[(size_t)k*ENCH+n] : 0.f;
            splitf(v,hi,lo); a1th[l]=(short)hi; a1tl[l]=(short)lo; }
    }
}

// ---- Kernel 2: FUSED 64-row pipeline: h1=gelu(BN(x)@W1+b1) (LDS only) ->
//      h2=gelu(h1@W2+b2) -> logits -> argmax. M=64/block, grid 512.
//      Same 53KB LDS & per-block staging as R5's gemm1; G2 consumes h1
//      chunk-by-chunk from LDS (h1 never touches global).
//      Blocks 0..255 append the edge bucket-scatter tail.
__global__ __launch_bounds__(256) void gemm123_k(const float* __restrict__ x,
    const float* __restrict__ stats, const float* __restrict__ gamma,
    const float* __restrict__ beta, const short* __restrict__ w1th,
    const short* __restrict__ w1tl, const float* __restrict__ b1,
    const short* __restrict__ w2th, const short* __restrict__ w2tl,
    const float* __restrict__ b2, const float* __restrict__ W3,
    const float* __restrict__ b3, int* __restrict__ ids,
    const int* __restrict__ ei, unsigned* __restrict__ ecnt,
    unsigned* __restrict__ earena)
{
    __shared__ float sc[256], sh[256];
    __shared__ __align__(16) unsigned char smem[51200];
    short* sAh = (short*)smem;                    // [64*40] (5120 B)
    short* sAl = sAh + 64*40;                     // [64*40]
    short* sBh = (short*)(smem + 10240);          // [256*40] (20480 B)
    short* sBl = sBh + 256*40;                    // [256*40]
    float* h2s = (float*)(smem + 10240);          // [64*132] f32 (33792 B)
    float* lgs = (float*)(smem + 44032);          // [64*20] f32 (5120 B)
    float* w3s = (float*)smem;                    // 2560 f32 (10240 B, sA region)

    int tid = threadIdx.x;
    {
        float mu  = stats[tid]*(1.0f/NT);
        float var = stats[256+tid]*(1.0f/NT) - mu*mu;
        float s = gamma[tid]/sqrtf(var + 1e-5f);
        sc[tid] = s; sh[tid] = beta[tid] - mu*s;
    }
    int row0 = blockIdx.x*64;
    int lane = tid&63, w = tid>>6;
    int ln = lane&15, quad = lane>>4;
    int m0w = (w&1)*32, nb1 = (w>>1)*128, nb2 = (w>>1)*64;

    // --- G1: h1 acc, 3-term split MFMA, K=256 -------------------------------
    f32x4 acc[2][8];
    #pragma unroll
    for(int i=0;i<2;i++)
        #pragma unroll
        for(int j=0;j<8;j++) acc[i][j] = (f32x4){0.f,0.f,0.f,0.f};
    float bias1[8];
    #pragma unroll
    for(int tn=0;tn<8;tn++) bias1[tn] = b1[nb1 + tn*16 + ln];

    float4 xa[2]; bf16x8 wb[8];
    #pragma unroll
    for(int i=0;i<2;i++){ int id=tid+i*256; int r=id>>3,kq=(id&7)*4;
        xa[i] = *(const float4*)&x[(size_t)(row0+r)*256 + kq]; }
    #pragma unroll
    for(int i=0;i<8;i++){ int id=tid+i*256; int plane=id>>10,cid=id&1023;
        int r=cid>>2,c=cid&3;
        wb[i] = *(const bf16x8*)((plane? w1tl:w1th) + (size_t)r*256 + c*8); }
    __syncthreads();
    for(int k0=0;k0<256;k0+=32){
        #pragma unroll
        for(int i=0;i<2;i++){                       // A: BN(x) split -> LDS
            int id = tid + i*256; int r = id>>3, kq = (id&7)*4;
            int k = k0+kq;
            float v0 = xa[i].x*sc[k]+sh[k],     v1 = xa[i].y*sc[k+1]+sh[k+1];
            float v2 = xa[i].z*sc[k+2]+sh[k+2], v3 = xa[i].w*sc[k+3]+sh[k+3];
            ushort4 hi, lo;
            splitf(v0,hi.x,lo.x); splitf(v1,hi.y,lo.y);
            splitf(v2,hi.z,lo.z); splitf(v3,hi.w,lo.w);
            *(ushort4*)&sAh[r*40+kq] = hi;
            *(ushort4*)&sAl[r*40+kq] = lo;
        }
        #pragma unroll
        for(int i=0;i<8;i++){                       // B regs -> LDS
            int id = tid + i*256; int plane = id>>10, cid = id&1023;
            int r = cid>>2, c = cid&3;
            *(bf16x8*)((plane? sBl : sBh) + r*40 + c*8) = wb[i];
        }
        __syncthreads();
        if(k0 < 224){                               // prefetch next K-tile
            #pragma unroll
            for(int i=0;i<2;i++){ int id=tid+i*256; int r=id>>3,kq=(id&7)*4;
                xa[i] = *(const float4*)&x[(size_t)(row0+r)*256 + k0+32+kq]; }
            #pragma unroll
            for(int i=0;i<8;i++){ int id=tid+i*256; int plane=id>>10,cid=id&1023;
                int r=cid>>2,c=cid&3;
                wb[i] = *(const bf16x8*)((plane? w1tl:w1th) + (size_t)r*256 + k0+32 + c*8); }
        }
        bf16x8 ah[2], al[2];
        #pragma unroll
        for(int tm=0;tm<2;tm++){
            ah[tm] = *(const bf16x8*)&sAh[(m0w+tm*16+ln)*40 + quad*8];
            al[tm] = *(const bf16x8*)&sAl[(m0w+tm*16+ln)*40 + quad*8];
        }
        #pragma unroll
        for(int tn=0;tn<8;tn++){
            bf16x8 bh = *(const bf16x8*)&sBh[(nb1+tn*16+ln)*40 + quad*8];
            bf16x8 bl = *(const bf16x8*)&sBl[(nb1+tn*16+ln)*40 + quad*8];
            #pragma unroll
            for(int tm=0;tm<2;tm++){
                acc[tm][tn] = __builtin_amdgcn_mfma_f32_16x16x32_bf16(al[tm], bh, acc[tm][tn], 0,0,0);
                acc[tm][tn] = __builtin_amdgcn_mfma_f32_16x16x32_bf16(ah[tm], bl, acc[tm][tn], 0,0,0);
                acc[tm][tn] = __builtin_amdgcn_mfma_f32_16x16x32_bf16(ah[tm], bh, acc[tm][tn], 0,0,0);
            }
        }
        __syncthreads();
    }

    // --- G2: h2 += split(h1_chunk) @ W2_chunk, 8 chunks of k=32 -------------
    f32x4 acc2[2][4];
    #pragma unroll
    for(int i=0;i<2;i++)
        #pragma unroll
        for(int j=0;j<4;j++) acc2[i][j] = (f32x4){0.f,0.f,0.f,0.f};
    bf16x8 wb2[4];
    #pragma unroll
    for(int i=0;i<4;i++){ int id=tid+i*256; int plane=id>>9,cid=id&511;
        int r=cid>>2,c=cid&3;
        wb2[i] = *(const bf16x8*)((plane? w2tl:w2th) + (size_t)r*256 + c*8); }
    #pragma unroll
    for(int cc=0;cc<8;cc++){
        if((w>>1) == (cc>>2)){                      // owner waves write h1 chunk
            int clp = cc&3;
            #pragma unroll
            for(int t=0;t<2;t++){
                int tn = 2*clp + t;
                #pragma unroll
                for(int tm=0;tm<2;tm++){
                    #pragma unroll
                    for(int r=0;r<4;r++){
                        int row = m0w + tm*16 + quad*4 + r;
                        float hv = gelu_f(acc[tm][tn][r] + bias1[tn]);
                        unsigned short hi, lo;
                        splitf(hv, hi, lo);
                        sAh[row*40 + t*16 + ln] = (short)hi;
                        sAl[row*40 + t*16 + ln] = (short)lo;
                    }
                }
            }
        }
        #pragma unroll
        for(int i=0;i<4;i++){                       // W2 tile regs -> LDS
            int id = tid + i*256; int plane = id>>9, cid = id&511;
            int r = cid>>2, c = cid&3;
            *(bf16x8*)((plane? sBl : sBh) + r*40 + c*8) = wb2[i];
        }
        __syncthreads();
        if(cc < 7){                                 // prefetch next W2 tile
            #pragma unroll
            for(int i=0;i<4;i++){ int id=tid+i*256; int plane=id>>9,cid=id&511;
                int r=cid>>2,c=cid&3;
                wb2[i] = *(const bf16x8*)((plane? w2tl:w2th)
                          + (size_t)r*256 + (cc+1)*32 + c*8); }
        }
        bf16x8 ah[2], al[2];
        #pragma unroll
        for(int tm=0;tm<2;tm++){
            ah[tm] = *(const bf16x8*)&sAh[(m0w+tm*16+ln)*40 + quad*8];
            al[tm] = *(const bf16x8*)&sAl[(m0w+tm*16+ln)*40 + quad*8];
        }
        #pragma unroll
        for(int tn=0;tn<4;tn++){
            bf16x8 bh = *(const bf16x8*)&sBh[(nb2+tn*16+ln)*40 + quad*8];
            bf16x8 bl = *(const bf16x8*)&sBl[(nb2+tn*16+ln)*40 + quad*8];
            #pragma unroll
            for(int tm=0;tm<2;tm++){
                acc2[tm][tn] = __builtin_amdgcn_mfma_f32_16x16x32_bf16(al[tm], bh, acc2[tm][tn], 0,0,0);
                acc2[tm][tn] = __builtin_amdgcn_mfma_f32_16x16x32_bf16(ah[tm], bl, acc2[tm][tn], 0,0,0);
                acc2[tm][tn] = __builtin_amdgcn_mfma_f32_16x16x32_bf16(ah[tm], bh, acc2[tm][tn], 0,0,0);
            }
        }
        __syncthreads();
    }

    // --- logits = h2@W3+b3; argmax (h2s overlays sB; w3s overlays sA) -------
    #pragma unroll
    for(int tn=0;tn<4;tn++){
        int col = nb2 + tn*16 + ln;
        float bias = b2[col];
        #pragma unroll
        for(int tm=0;tm<2;tm++){
            int rb = m0w + tm*16 + quad*4;
            #pragma unroll
            for(int r=0;r<4;r++)
                h2s[(rb+r)*132 + col] = gelu_f(acc2[tm][tn][r] + bias);
        }
    }
    for(int l=tid;l<2560;l+=256) w3s[l] = W3[l];
    __syncthreads();
    {
        int n = tid>>2, q = tid&3;
        float lg[5] = {};
        #pragma unroll 4
        for(int k=0;k<128;k++){
            float h = h2s[n*132+k];
            #pragma unroll
            for(int a=0;a<5;a++) lg[a] += h*w3s[k*20 + q*5 + a];
        }
        #pragma unroll
        for(int a=0;a<5;a++) lgs[n*20 + q*5 + a] = lg[a] + b3[q*5+a];
    }
    __syncthreads();
    if(tid<64){                                     // numpy argmax: first max
        float best = lgs[tid*20]; int bi = 0;
        #pragma unroll
        for(int a=1;a<20;a++){ float v2 = lgs[tid*20+a]; if(v2>best){best=v2;bi=a;} }
        ids[row0+tid] = bi;
    }

    // ---- edge bucket-scatter tail (blocks 0..255; 4096 edges each) --------
    if(blockIdx.x < 256){
        __syncthreads();                     // w3s/sA dead -> reuse as counters
        unsigned* lcnt  = (unsigned*)sAh;    // 512 u32
        unsigned* gbase = ((unsigned*)sAh) + 512;
        for(int l=tid; l<512; l+=256) lcnt[l] = 0;
        __syncthreads();
        int ebase = blockIdx.x * 4096;
        #pragma unroll 4
        for(int i=0;i<16;i++){
            int e = ebase + i*256 + tid;
            int s = ei[e], d = ei[Ee+e];
            if((s>>11)==(d>>11)) atomicAdd(&lcnt[s>>6], 1u);
        }
        __syncthreads();
        for(int l=tid; l<512; l+=256){
            unsigned c = lcnt[l];
            gbase[l] = c ? atomicAdd(&ecnt[l], c) : 0u;
            lcnt[l] = 0;
        }
        __syncthreads();
        #pragma unroll 4
        for(int i=0;i<16;i++){
            int e = ebase + i*256 + tid;
            int s = ei[e], d = ei[Ee+e];
            if((s>>11)==(d>>11)){
                int bin = s>>6;
                unsigned r = atomicAdd(&lcnt[bin], 1u);
                unsigned pos = gbase[bin] + r;
                if(pos < BINCAP)
                    earena[(size_t)bin*BINCAP + pos] =
                        ((unsigned)(s&63)<<11) | (unsigned)(d&2047);
            }
        }
    }
}

// ---- Kernel 3: LDS adjacency rebuild + aggregation + hout GEMM + heads -----
// grid 512 (64 nodes each = bucket blockIdx). 4 waves.
__global__ __launch_bounds__(256) void msg3_k(
    const int* __restrict__ ids, const unsigned* __restrict__ ecnt,
    const unsigned* __restrict__ earena, const float* __restrict__ embed,
    const short* __restrict__ wmth, const short* __restrict__ wmtl,
    const float* __restrict__ b_msg, const float* __restrict__ w_coor,
    const short* __restrict__ a1th, const short* __restrict__ a1tl,
    const float* __restrict__ a1v, const float* __restrict__ A2,
    const float* __restrict__ a2v, const float* __restrict__ dalpha,
    const float* __restrict__ dw, const float* __restrict__ db,
    const float* __restrict__ coords, float* __restrict__ out_ang,
    float* __restrict__ out_z, float* __restrict__ out_co)
{
    __shared__ unsigned short v_bf[64*136];    // v bf16 (row pad 136)
    __shared__ unsigned short houts[64*136];   // hout bf16; later t1s [64][104]
    // arena phase 0/1: lmask u32[4096] | ind u32[1280] | sid u8[2048] | emb f32[2560]
    // GEMM phases:     sBh[10240 B] | sBl[10240 B] (overlays lmask+ind)
    __shared__ __align__(16) unsigned char arena[33792];
    __shared__ float s_bm[128], s_wc[384], s_A2[624], s_a1[104];
    __shared__ float s_dyt[16], s_a2[8];

    unsigned*       lmask = (unsigned*)arena;
    unsigned*       ind   = (unsigned*)(arena + 16384);
    unsigned char*  sid   = arena + 21504;
    float*          emb   = (float*)(arena + 23552);
    short*          sBh   = (short*)arena;
    short*          sBl   = (short*)(arena + 10240);

    int tid = threadIdx.x;
    int bin = blockIdx.x;
    int row0 = bin*64;
    int g = blockIdx.x>>5, tile = blockIdx.x&31;
    int lane = tid&63, w = tid>>6;
    int ln = lane&15, quad = lane>>4;
    int m0w = (w&1)*32, n0w = (w>>1)*64;

    // --- phase 0: constants + emb + sid + zero lmask ------------------------
    for(int l=tid;l<NATOMS*128;l+=256) emb[l] = embed[l];
    #pragma unroll
    for(int i=0;i<8;i++){ int j = tid + i*256; sid[j] = (unsigned char)ids[g*Nn + j]; }
    #pragma unroll
    for(int i=0;i<16;i++) lmask[tid + i*256] = 0;
    if(tid<128) s_bm[tid] = b_msg[tid];
    if(tid<104) s_a1[tid] = (tid<ENCH) ? a1v[tid] : 0.f;
    for(int l=tid;l<384;l+=256) s_wc[l] = w_coor[l];
    for(int l=tid;l<624;l+=256) s_A2[l] = (l<600) ? A2[l] : 0.f;
    if(tid==0)  s_dyt[0] = dalpha[0];
    if(tid<6){ s_dyt[1+tid] = dw[tid]; s_dyt[8+tid] = db[tid]; }
    if(tid<8)  s_a2[tid] = (tid<6) ? a2v[tid] : 0.f;
    int nb = min((int)ecnt[bin], BINCAP);
    __syncthreads();

    // --- phase 1: ballot indicator bitmasks + LDS adjacency build -----------
    for(int wp=w; wp<32; wp+=4){
        int a = sid[wp*64 + lane];
        #pragma unroll
        for(int atom=0; atom<NATOMS; atom++){
            unsigned long long bm = __ballot(a==atom);
            if(lane<2) ind[atom*64 + wp*2 + lane] = (unsigned)(bm >> (32*lane));
        }
    }
    for(int i=tid; i<nb; i+=256){
        unsigned wv = earena[(size_t)bin*BINCAP + i];
        int sl = wv>>11, dl = wv & 2047;
        atomicOr(&lmask[sl*64 + (dl>>5)], 1u<<(dl&31));
    }
    __syncthreads();

    // --- phase 2: per-node counts popcount(lmask & ind), 4-lane split -------
    int node = tid>>2, p = tid&3;
    unsigned mw[16];
    {
        const unsigned* mrow = &lmask[node*64 + p*16];
        *(uint4*)&mw[0]  = *(const uint4*)&mrow[0];
        *(uint4*)&mw[4]  = *(const uint4*)&mrow[4];
        *(uint4*)&mw[8]  = *(const uint4*)&mrow[8];
        *(uint4*)&mw[12] = *(const uint4*)&mrow[12];
    }
    int degi = 0;
    #pragma unroll
    for(int w2=0;w2<16;w2++) degi += __popc(mw[w2]);
    float cnt[NATOMS];
    #pragma unroll
    for(int a=0;a<NATOMS;a++){
        int c = 0;
        const unsigned* ia = &ind[a*64 + p*16];
        #pragma unroll
        for(int w2=0;w2<16;w2++) c += __popc(mw[w2] & ia[w2]);
        cnt[a] = (float)c;
    }
    #pragma unroll
    for(int a=0;a<NATOMS;a++){
        cnt[a] += __shfl_xor(cnt[a],1,64);
        cnt[a] += __shfl_xor(cnt[a],2,64);
    }
    float deg = (float)degi;
    deg += __shfl_xor(deg,1,64);
    deg += __shfl_xor(deg,2,64);

    // --- v = emb[own] + (sum_a cnt_a emb_a)/max(deg,1) -> LDS bf16 ----------
    {
        float inv = 1.0f / fmaxf(deg, 1.0f);
        int oid = sid[tile*64 + node];
        int d0 = p*32;
        float vv[32];
        #pragma unroll
        for(int d=0;d<32;d++) vv[d]=0.f;
        #pragma unroll
        for(int a=0;a<NATOMS;a++){
            float ca = cnt[a];
            const float* ea = &emb[a*128 + d0];
            #pragma unroll
            for(int d=0;d<32;d+=4){
                float4 e = *(const float4*)&ea[d];
                vv[d]+=ca*e.x; vv[d+1]+=ca*e.y; vv[d+2]+=ca*e.z; vv[d+3]+=ca*e.w;
            }
        }
        const float* eo = &emb[oid*128 + d0];
        unsigned short* dst = &v_bf[node*136 + d0];
        #pragma unroll
        for(int d=0;d<32;d+=4){
            float4 e = *(const float4*)&eo[d];
            ushort4 o;
            o.x = f2b(e.x + vv[d]*inv);
            o.y = f2b(e.y + vv[d+1]*inv);
            o.z = f2b(e.z + vv[d+2]*inv);
            o.w = f2b(e.w + vv[d+3]*inv);
            *(ushort4*)&dst[d] = o;
        }
    }
    __syncthreads();     // v complete; lmask/ind/sid/emb dead -> arena = sB

    // ---- hout = gelu(v @ W_msg + b), 2-term W split, A direct from v_bf ----
    f32x4 acc[2][4];
    #pragma unroll
    for(int i=0;i<2;i++)
        #pragma unroll
        for(int j=0;j<4;j++) acc[i][j] = (f32x4){0.f,0.f,0.f,0.f};
    for(int k0=0;k0<128;k0+=32){
        #pragma unroll
        for(int i=0;i<4;i++){                           // B: Wmsg_t [128][32]
            int id = tid + i*256; int plane = id>>9, cid = id&511;
            int r = cid>>2, c = cid&3;
            const short* src = (plane? wmtl : wmth) + (size_t)r*128 + k0 + c*8;
            short* dst = (plane? sBl : sBh) + r*40 + c*8;
            *(bf16x8*)dst = *(const bf16x8*)src;
        }
        __syncthreads();
        bf16x8 av[2];
        #pragma unroll
        for(int tm=0;tm<2;tm++)
            av[tm] = *(const bf16x8*)&v_bf[(m0w+tm*16+ln)*136 + k0 + quad*8];
        #pragma unroll
        for(int tn=0;tn<4;tn++){
            bf16x8 bh = *(const bf16x8*)&sBh[(n0w+tn*16+ln)*40 + quad*8];
            bf16x8 bl = *(const bf16x8*)&sBl[(n0w+tn*16+ln)*40 + quad*8];
            #pragma unroll
            for(int tm=0;tm<2;tm++){
                acc[tm][tn] = __builtin_amdgcn_mfma_f32_16x16x32_bf16(av[tm], bl, acc[tm][tn], 0,0,0);
                acc[tm][tn] = __builtin_amdgcn_mfma_f32_16x16x32_bf16(av[tm], bh, acc[tm][tn], 0,0,0);
            }
        }
        __syncthreads();
    }
    // epilogue: z fp32 + hout bf16 to LDS
    #pragma unroll
    for(int tn=0;tn<4;tn++){
        int col = n0w + tn*16 + ln;
        float bias = s_bm[col];
        #pragma unroll
        for(int tm=0;tm<2;tm++){
            int mb2 = m0w + tm*16 + quad*4;
            #pragma unroll
            for(int r=0;r<4;r++){
                float hv = gelu_f(acc[tm][tn][r] + bias);
                out_z[(size_t)(row0+mb2+r)*128 + col] = hv;
                houts[(mb2+r)*136 + col] = f2b(hv);
            }
        }
    }
    __syncthreads();

    // ---- coors: 4-lane k-split dot with w_coor -----------------------------
    {
        float d0=0.f, d1=0.f, d2=0.f;
        int kb = p*32;
        #pragma unroll
        for(int k=0;k<32;k+=4){
            ushort4 hv = *(const ushort4*)&houts[node*136 + kb + k];
            float h0=b2f(hv.x),h1=b2f(hv.y),h2=b2f(hv.z),h3=b2f(hv.w);
            const float* wc = &s_wc[(kb+k)*3];
            d0 += h0*wc[0]+h1*wc[3]+h2*wc[6]+h3*wc[9];
            d1 += h0*wc[1]+h1*wc[4]+h2*wc[7]+h3*wc[10];
            d2 += h0*wc[2]+h1*wc[5]+h2*wc[8]+h3*wc[11];
        }
        d0 += __shfl_xor(d0,1,64); d0 += __shfl_xor(d0,2,64);
        d1 += __shfl_xor(d1,1,64); d1 += __shfl_xor(d1,2,64);
        d2 += __shfl_xor(d2,1,64); d2 += __shfl_xor(d2,2,64);
        if(p==0){
            size_t o = (size_t)(row0+node)*3;
            out_co[o+0] = coords[o+0] + tanhf(d0);
            out_co[o+1] = coords[o+1] + tanhf(d1);
            out_co[o+2] = coords[o+2] + tanhf(d2);
        }
    }

    // ---- t1 = gelu(hout @ A1 + a1), 2-term split, N=128 (cols>=100 zero) ---
    f32x4 acc2[2][4];
    #pragma unroll
    for(int i=0;i<2;i++)
        #pragma unroll
        for(int j=0;j<4;j++) acc2[i][j] = (f32x4){0.f,0.f,0.f,0.f};
    for(int k0=0;k0<128;k0+=32){
        __syncthreads();                    // protect sB reuse across iters
        #pragma unroll
        for(int i=0;i<4;i++){
            int id = tid + i*256; int plane = id>>9, cid = id&511;
            int r = cid>>2, c = cid&3;
            const short* src = (plane? a1tl : a1th) + (size_t)r*128 + k0 + c*8;
            short* dst = (plane? sBl : sBh) + r*40 + c*8;
            *(bf16x8*)dst = *(const bf16x8*)src;
        }
        __syncthreads();
        bf16x8 ah[2];
        #pragma unroll
        for(int tm=0;tm<2;tm++)
            ah[tm] = *(const bf16x8*)&houts[(m0w+tm*16+ln)*136 + k0 + quad*8];
        #pragma unroll
        for(int tn=0;tn<4;tn++){
            bf16x8 bh = *(const bf16x8*)&sBh[(n0w+tn*16+ln)*40 + quad*8];
            bf16x8 bl = *(const bf16x8*)&sBl[(n0w+tn*16+ln)*40 + quad*8];
            #pragma unroll
            for(int tm=0;tm<2;tm++){
                acc2[tm][tn] = __builtin_amdgcn_mfma_f32_16x16x32_bf16(ah[tm], bl, acc2[tm][tn], 0,0,0);
                acc2[tm][tn] = __builtin_amdgcn_mfma_f32_16x16x32_bf16(ah[tm], bh, acc2[tm][tn], 0,0,0);
            }
        }
    }
    __syncthreads();                        // houts reads done -> reuse as t1s
    unsigned short* t1s = houts;            // [64][104]
    #pragma unroll
    for(int tn=0;tn<4;tn++){
        int col = n0w + tn*16 + ln;
        if(col < 104){
            float bias = s_a1[col];
            #pragma unroll
            for(int tm=0;tm<2;tm++){
                int mb2 = m0w + tm*16 + quad*4;
                #pragma unroll
                for(int r=0;r<4;r++)
                    t1s[(mb2+r)*104 + col] = f2b(gelu_f(acc2[tm][tn][r] + bias));
            }
        }
    }
    __syncthreads();

    // ---- t2 = gelu(t1@A2+a2); DyT; angles ----------------------------------
    {
        int g0 = (p<2) ? p*7 : 14+(p-2)*6;
        int gcount = (p<2) ? 7 : 6;
        float s[6] = {0.f,0.f,0.f,0.f,0.f,0.f};
        for(int gg=0; gg<gcount; gg++){
            int kb = (g0+gg)*4;
            ushort4 tv = *(const ushort4*)&t1s[node*104 + kb];
            float u0=b2f(tv.x), u1=b2f(tv.y), u2=b2f(tv.z), u3=b2f(tv.w);
            #pragma unroll
            for(int j=0;j<6;j++)
                s[j] += u0*s_A2[kb*6+j] + u1*s_A2[(kb+1)*6+j]
                      + u2*s_A2[(kb+2)*6+j] + u3*s_A2[(kb+3)*6+j];
        }
        #pragma unroll
        for(int j=0;j<6;j++){ s[j]+=__shfl_xor(s[j],1,64); s[j]+=__shfl_xor(s[j],2,64); }
        if(p<2){
            size_t o = (size_t)(row0+node)*6 + p*3;
            #pragma unroll
            for(int jj=0;jj<3;jj++){
                int j = p*3+jj;
                float t2v = gelu_f(s[j] + s_a2[j]);
                float uu = tanhf(s_dyt[0]*t2v)*s_dyt[1+j] + s_dyt[8+j];
                out_ang[o+jj] = tanhf(uu);
            }
        }
    }
}

// ---------------------------------------------------------------------------
extern "C" void kernel_launch(void* const* d_in, const int* in_sizes, int n_in,
                              void* d_out, int out_size, void* d_ws, size_t ws_size,
                              hipStream_t stream) {
    const float* x      = (const float*)d_in[0];
    const float* coords = (const float*)d_in[1];
    const int*   ei     = (const int*)d_in[2];
    const float* gamma  = (const float*)d_in[4];
    const float* beta   = (const float*)d_in[5];
    const float* W1     = (const float*)d_in[6];
    const float* b1     = (const float*)d_in[7];
    const float* W2     = (const float*)d_in[8];
    const float* b2     = (const float*)d_in[9];
    const float* W3     = (const float*)d_in[10];
    const float* b3     = (const float*)d_in[11];
    const float* embed  = (const float*)d_in[12];
    const float* W_msg  = (const float*)d_in[13];
    const float* b_msg  = (const float*)d_in[14];
    const float* w_coor = (const float*)d_in[15];
    const float* A1     = (const float*)d_in[16];
    const float* a1v    = (const float*)d_in[17];
    const float* A2     = (const float*)d_in[18];
    const float* a2v    = (const float*)d_in[19];
    const float* dalpha = (const float*)d_in[20];
    const float* dw     = (const float*)d_in[21];
    const float* db     = (const float*)d_in[22];

    // ws layout (~7.3 MB peak):
    //  0      : ids   (128 KB)
    //  128K   : stats (2 KB) + ecnt (2 KB)   <- one 4 KB memset
    //  256K   : weight planes (512 KB)
    //  1M     : earena u32[512*3072] (6 MB)
    char* ws = (char*)d_ws;
    int*      ids   = (int*)ws;
    float*    stats = (float*)(ws + 131072);
    unsigned* ecnt  = (unsigned*)(ws + 131072 + 2048);
    short*    w1th  = (short*)(ws + 262144);
    short*    w1tl  = w1th + 65536;
    short*    w2th  = w1tl + 65536;
    short*    w2tl  = w2th + 32768;
    short*    wmth  = w2tl + 32768;
    short*    wmtl  = wmth + 16384;
    short*    a1th  = wmtl + 16384;
    short*    a1tl  = a1th + 16384;
    unsigned* earena = (unsigned*)(ws + (1<<20));

    float* out_ang = (float*)d_out;
    float* out_z   = out_ang + (size_t)NT*OUTC;
    float* out_co  = out_z   + (size_t)NT*DIMd;

    hipMemsetAsync(stats, 0, 4096, stream);      // stats + ecnt
    prep0_k<<<320, 256, 0, stream>>>(x, stats, W1, W2, W_msg, A1,
        w1th, w1tl, w2th, w2tl, wmth, wmtl, a1th, a1tl);
    gemm123_k<<<512, 256, 0, stream>>>(x, stats, gamma, beta, w1th, w1tl, b1,
        w2th, w2tl, b2, W3, b3, ids, ei, ecnt, earena);
    msg3_k<<<512, 256, 0, stream>>>(ids, ecnt, earena, embed, wmth, wmtl, b_msg,
        w_coor, a1th, a1tl, a1v, A2, a2v, dalpha, dw, db, coords,
        out_ang, out_z, out_co);
}

// Round 8
// 261.258 us; speedup vs baseline: 1.2152x; 1.0262x over previous
//
#include <hip/hip_runtime.h>
#include <hip/hip_bf16.h>
#include <math.h>

// Problem constants (match reference)
#define Bg 16
#define Nn 2048
#define Ee (1<<20)
#define NT (Bg*Nn)
#define INC 256
#define DIMd 128
#define OUTC 6
#define ENCH 100
#define NATOMS 20
#define BINCAP 3072   // per-bin edge capacity: mean 2048, sigma~44 -> +23 sigma

typedef __attribute__((ext_vector_type(8))) short bf16x8;
typedef __attribute__((ext_vector_type(4))) float f32x4;

__device__ __forceinline__ float gelu_f(float x){
    return 0.5f*x*(1.0f+erff(x*0.70710678118654752440f));
}
__device__ __forceinline__ unsigned short f2b(float f){
    __hip_bfloat16 h = __float2bfloat16(f);
    return *(unsigned short*)&h;
}
__device__ __forceinline__ float b2f(unsigned short u){
    unsigned v = ((unsigned)u)<<16;
    return __uint_as_float(v);
}
// split fp32 into bf16 hi + bf16 lo (v ~= hi + lo, dropped residual ~2^-18 rel)
__device__ __forceinline__ void splitf(float v, unsigned short& hi, unsigned short& lo){
    unsigned short h = f2b(v);
    hi = h; lo = f2b(v - b2f(h));
}

// ---- Kernel 1: prep0 = BN stats (blocks 0..255) + coalesced LDS-transpose
//      weight split (blocks 256..287: W1 x16, W2 x8, Wm x4, A1 x4 tiles) -----
__global__ __launch_bounds__(256) void prep0_k(const float* __restrict__ x,
    float* __restrict__ stats, const float* __restrict__ W1,
    const float* __restrict__ W2, const float* __restrict__ Wm,
    const float* __restrict__ A1, short* __restrict__ w1th, short* __restrict__ w1tl,
    short* __restrict__ w2th, short* __restrict__ w2tl,
    short* __restrict__ wmth, short* __restrict__ wmtl,
    short* __restrict__ a1th, short* __restrict__ a1tl)
{
    __shared__ float st[64*65];   // transpose tile, pad-65 (bank-conflict-free)
    int bx = blockIdx.x, tid = threadIdx.x;
    if(bx < 256){
        int c = tid;
        int r0 = bx * 128;
        const float* p = x + (size_t)r0*INC + c;
        float s = 0.f, s2 = 0.f;
        #pragma unroll 8
        for(int r=0;r<128;r++){ float v = p[(size_t)r*INC]; s += v; s2 += v*v; }
        atomicAdd(&stats[c], s);
        atomicAdd(&stats[INC+c], s2);
        return;
    }
    // 64x64 tile transpose+split: src [K][N] row-major -> dst [N][K] hi/lo
    int t = bx - 256;
    const float* src; short *dh, *dl;
    int k0, n0, lds, ldd, nmax;
    if(t < 16){        src=W1; dh=w1th; dl=w1tl; lds=256; ldd=256; nmax=256;
                       k0=(t>>2)*64;      n0=(t&3)*64; }
    else if(t < 24){   int u=t-16; src=W2; dh=w2th; dl=w2tl; lds=128; ldd=256; nmax=128;
                       k0=(u>>1)*64;      n0=(u&1)*64; }
    else if(t < 28){   int u=t-24; src=Wm; dh=wmth; dl=wmtl; lds=128; ldd=128; nmax=128;
                       k0=(u>>1)*64;      n0=(u&1)*64; }
    else {             int u=t-28; src=A1; dh=a1th; dl=a1tl; lds=100; ldd=128; nmax=100;
                       k0=(u>>1)*64;      n0=(u&1)*64; }
    #pragma unroll
    for(int i=0;i<16;i++){                 // coalesced read rows
        int idx = tid + i*256; int r = idx>>6, c = idx&63;
        float v = (n0+c < nmax) ? src[(size_t)(k0+r)*lds + n0+c] : 0.f;
        st[r*65+c] = v;
    }
    __syncthreads();
    #pragma unroll
    for(int i=0;i<16;i++){                 // coalesced write transposed+split
        int idx = tid + i*256; int rr = idx>>6, cc = idx&63;
        unsigned short hi, lo;
        splitf(st[cc*65+rr], hi, lo);
        size_t o = (size_t)(n0+rr)*ldd + k0+cc;
        dh[o] = (short)hi; dl[o] = (short)lo;
    }
}

// ---- Kernel 2: FUSED 64-row pipeline: h1=gelu(BN(x)@W1+b1) (LDS only) ->
//      h2=gelu(h1@W2+b2) -> logits -> argmax. M=64/block, grid 512.
//      G1 uses DEPTH-2 register prefetch (loads issued 2 K-iters ahead).
//      Blocks 0..255 append the edge bucket-scatter tail.
__global__ __launch_bounds__(256) void gemm123_k(const float* __restrict__ x,
    const float* __restrict__ stats, const float* __restrict__ gamma,
    const float* __restrict__ beta, const short* __restrict__ w1th,
    const short* __restrict__ w1tl, const float* __restrict__ b1,
    const short* __restrict__ w2th, const short* __restrict__ w2tl,
    const float* __restrict__ b2, const float* __restrict__ W3,
    const float* __restrict__ b3, int* __restrict__ ids,
    const int* __restrict__ ei, unsigned* __restrict__ ecnt,
    unsigned* __restrict__ earena)
{
    __shared__ float sc[256], sh[256];
    __shared__ __align__(16) unsigned char smem[51200];
    short* sAh = (short*)smem;                    // [64*40] (5120 B)
    short* sAl = sAh + 64*40;                     // [64*40]
    short* sBh = (short*)(smem + 10240);          // [256*40] (20480 B)
    short* sBl = sBh + 256*40;                    // [256*40]
    float* h2s = (float*)(smem + 10240);          // [64*132] f32 (33792 B)
    float* lgs = (float*)(smem + 44032);          // [64*20] f32 (5120 B)
    float* w3s = (float*)smem;                    // 2560 f32 (10240 B, sA region)

    int tid = threadIdx.x;
    {
        float mu  = stats[tid]*(1.0f/NT);
        float var = stats[256+tid]*(1.0f/NT) - mu*mu;
        float s = gamma[tid]/sqrtf(var + 1e-5f);
        sc[tid] = s; sh[tid] = beta[tid] - mu*s;
    }
    int row0 = blockIdx.x*64;
    int lane = tid&63, w = tid>>6;
    int ln = lane&15, quad = lane>>4;
    int m0w = (w&1)*32, nb1 = (w>>1)*128, nb2 = (w>>1)*64;

    // --- G1: h1 acc, 3-term split MFMA, K=256, depth-2 prefetch -------------
    f32x4 acc[2][8];
    #pragma unroll
    for(int i=0;i<2;i++)
        #pragma unroll
        for(int j=0;j<8;j++) acc[i][j] = (f32x4){0.f,0.f,0.f,0.f};
    float bias1[8];
    #pragma unroll
    for(int tn=0;tn<8;tn++) bias1[tn] = b1[nb1 + tn*16 + ln];

    float4 xa[2][2]; bf16x8 wb[2][8];
    #pragma unroll
    for(int t=0;t<2;t++){                        // preload K-tiles 0 and 1
        #pragma unroll
        for(int i=0;i<2;i++){ int id=tid+i*256; int r=id>>3,kq=(id&7)*4;
            xa[t][i] = *(const float4*)&x[(size_t)(row0+r)*256 + t*32 + kq]; }
        #pragma unroll
        for(int i=0;i<8;i++){ int id=tid+i*256; int plane=id>>10,cid=id&1023;
            int r=cid>>2,c=cid&3;
            wb[t][i] = *(const bf16x8*)((plane? w1tl:w1th) + (size_t)r*256 + t*32 + c*8); }
    }
    __syncthreads();
    for(int k0=0;k0<256;k0+=32){
        int cur = (k0>>5)&1;
        #pragma unroll
        for(int i=0;i<2;i++){                       // A: BN(x) split -> LDS
            int id = tid + i*256; int r = id>>3, kq = (id&7)*4;
            int k = k0+kq;
            float v0 = xa[cur][i].x*sc[k]+sh[k],     v1 = xa[cur][i].y*sc[k+1]+sh[k+1];
            float v2 = xa[cur][i].z*sc[k+2]+sh[k+2], v3 = xa[cur][i].w*sc[k+3]+sh[k+3];
            ushort4 hi, lo;
            splitf(v0,hi.x,lo.x); splitf(v1,hi.y,lo.y);
            splitf(v2,hi.z,lo.z); splitf(v3,hi.w,lo.w);
            *(ushort4*)&sAh[r*40+kq] = hi;
            *(ushort4*)&sAl[r*40+kq] = lo;
        }
        #pragma unroll
        for(int i=0;i<8;i++){                       // B regs -> LDS
            int id = tid + i*256; int plane = id>>10, cid = id&1023;
            int r = cid>>2, c = cid&3;
            *(bf16x8*)((plane? sBl : sBh) + r*40 + c*8) = wb[cur][i];
        }
        __syncthreads();
        if(k0 < 192){                               // prefetch K-tile k0+64
            #pragma unroll
            for(int i=0;i<2;i++){ int id=tid+i*256; int r=id>>3,kq=(id&7)*4;
                xa[cur][i] = *(const float4*)&x[(size_t)(row0+r)*256 + k0+64+kq]; }
            #pragma unroll
            for(int i=0;i<8;i++){ int id=tid+i*256; int plane=id>>10,cid=id&1023;
                int r=cid>>2,c=cid&3;
                wb[cur][i] = *(const bf16x8*)((plane? w1tl:w1th) + (size_t)r*256 + k0+64 + c*8); }
        }
        bf16x8 ah[2], al[2];
        #pragma unroll
        for(int tm=0;tm<2;tm++){
            ah[tm] = *(const bf16x8*)&sAh[(m0w+tm*16+ln)*40 + quad*8];
            al[tm] = *(const bf16x8*)&sAl[(m0w+tm*16+ln)*40 + quad*8];
        }
        #pragma unroll
        for(int tn=0;tn<8;tn++){
            bf16x8 bh = *(const bf16x8*)&sBh[(nb1+tn*16+ln)*40 + quad*8];
            bf16x8 bl = *(const bf16x8*)&sBl[(nb1+tn*16+ln)*40 + quad*8];
            #pragma unroll
            for(int tm=0;tm<2;tm++){
                acc[tm][tn] = __builtin_amdgcn_mfma_f32_16x16x32_bf16(al[tm], bh, acc[tm][tn], 0,0,0);
                acc[tm][tn] = __builtin_amdgcn_mfma_f32_16x16x32_bf16(ah[tm], bl, acc[tm][tn], 0,0,0);
                acc[tm][tn] = __builtin_amdgcn_mfma_f32_16x16x32_bf16(ah[tm], bh, acc[tm][tn], 0,0,0);
            }
        }
        __syncthreads();
    }

    // --- G2: h2 += split(h1_chunk) @ W2_chunk, 8 chunks of k=32 -------------
    f32x4 acc2[2][4];
    #pragma unroll
    for(int i=0;i<2;i++)
        #pragma unroll
        for(int j=0;j<4;j++) acc2[i][j] = (f32x4){0.f,0.f,0.f,0.f};
    bf16x8 wb2[4];
    #pragma unroll
    for(int i=0;i<4;i++){ int id=tid+i*256; int plane=id>>9,cid=id&511;
        int r=cid>>2,c=cid&3;
        wb2[i] = *(const bf16x8*)((plane? w2tl:w2th) + (size_t)r*256 + c*8); }
    #pragma unroll
    for(int cc=0;cc<8;cc++){
        if((w>>1) == (cc>>2)){                      // owner waves write h1 chunk
            int clp = cc&3;
            #pragma unroll
            for(int t=0;t<2;t++){
                int tn = 2*clp + t;
                #pragma unroll
                for(int tm=0;tm<2;tm++){
                    #pragma unroll
                    for(int r=0;r<4;r++){
                        int row = m0w + tm*16 + quad*4 + r;
                        float hv = gelu_f(acc[tm][tn][r] + bias1[tn]);
                        unsigned short hi, lo;
                        splitf(hv, hi, lo);
                        sAh[row*40 + t*16 + ln] = (short)hi;
                        sAl[row*40 + t*16 + ln] = (short)lo;
                    }
                }
            }
        }
        #pragma unroll
        for(int i=0;i<4;i++){                       // W2 tile regs -> LDS
            int id = tid + i*256; int plane = id>>9, cid = id&511;
            int r = cid>>2, c = cid&3;
            *(bf16x8*)((plane? sBl : sBh) + r*40 + c*8) = wb2[i];
        }
        __syncthreads();
        if(cc < 7){                                 // prefetch next W2 tile
            #pragma unroll
            for(int i=0;i<4;i++){ int id=tid+i*256; int plane=id>>9,cid=id&511;
                int r=cid>>2,c=cid&3;
                wb2[i] = *(const bf16x8*)((plane? w2tl:w2th)
                          + (size_t)r*256 + (cc+1)*32 + c*8); }
        }
        bf16x8 ah[2], al[2];
        #pragma unroll
        for(int tm=0;tm<2;tm++){
            ah[tm] = *(const bf16x8*)&sAh[(m0w+tm*16+ln)*40 + quad*8];
            al[tm] = *(const bf16x8*)&sAl[(m0w+tm*16+ln)*40 + quad*8];
        }
        #pragma unroll
        for(int tn=0;tn<4;tn++){
            bf16x8 bh = *(const bf16x8*)&sBh[(nb2+tn*16+ln)*40 + quad*8];
            bf16x8 bl = *(const bf16x8*)&sBl[(nb2+tn*16+ln)*40 + quad*8];
            #pragma unroll
            for(int tm=0;tm<2;tm++){
                acc2[tm][tn] = __builtin_amdgcn_mfma_f32_16x16x32_bf16(al[tm], bh, acc2[tm][tn], 0,0,0);
                acc2[tm][tn] = __builtin_amdgcn_mfma_f32_16x16x32_bf16(ah[tm], bl, acc2[tm][tn], 0,0,0);
                acc2[tm][tn] = __builtin_amdgcn_mfma_f32_16x16x32_bf16(ah[tm], bh, acc2[tm][tn], 0,0,0);
            }
        }
        __syncthreads();
    }

    // --- logits = h2@W3+b3; argmax (h2s overlays sB; w3s overlays sA) -------
    #pragma unroll
    for(int tn=0;tn<4;tn++){
        int col = nb2 + tn*16 + ln;
        float bias = b2[col];
        #pragma unroll
        for(int tm=0;tm<2;tm++){
            int rb = m0w + tm*16 + quad*4;
            #pragma unroll
            for(int r=0;r<4;r++)
                h2s[(rb+r)*132 + col] = gelu_f(acc2[tm][tn][r] + bias);
        }
    }
    for(int l=tid;l<2560;l+=256) w3s[l] = W3[l];
    __syncthreads();
    {
        int n = tid>>2, q = tid&3;
        float lg[5] = {};
        #pragma unroll 4
        for(int k=0;k<128;k++){
            float h = h2s[n*132+k];
            #pragma unroll
            for(int a=0;a<5;a++) lg[a] += h*w3s[k*20 + q*5 + a];
        }
        #pragma unroll
        for(int a=0;a<5;a++) lgs[n*20 + q*5 + a] = lg[a] + b3[q*5+a];
    }
    __syncthreads();
    if(tid<64){                                     // numpy argmax: first max
        float best = lgs[tid*20]; int bi = 0;
        #pragma unroll
        for(int a=1;a<20;a++){ float v2 = lgs[tid*20+a]; if(v2>best){best=v2;bi=a;} }
        ids[row0+tid] = bi;
    }

    // ---- edge bucket-scatter tail (blocks 0..255; 4096 edges each) --------
    if(blockIdx.x < 256){
        __syncthreads();                     // w3s/sA dead -> reuse as counters
        unsigned* lcnt  = (unsigned*)sAh;    // 512 u32
        unsigned* gbase = ((unsigned*)sAh) + 512;
        for(int l=tid; l<512; l+=256) lcnt[l] = 0;
        __syncthreads();
        int ebase = blockIdx.x * 4096;
        #pragma unroll 4
        for(int i=0;i<16;i++){
            int e = ebase + i*256 + tid;
            int s = ei[e], d = ei[Ee+e];
            if((s>>11)==(d>>11)) atomicAdd(&lcnt[s>>6], 1u);
        }
        __syncthreads();
        for(int l=tid; l<512; l+=256){
            unsigned c = lcnt[l];
            gbase[l] = c ? atomicAdd(&ecnt[l], c) : 0u;
            lcnt[l] = 0;
        }
        __syncthreads();
        #pragma unroll 4
        for(int i=0;i<16;i++){
            int e = ebase + i*256 + tid;
            int s = ei[e], d = ei[Ee+e];
            if((s>>11)==(d>>11)){
                int bin = s>>6;
                unsigned r = atomicAdd(&lcnt[bin], 1u);
                unsigned pos = gbase[bin] + r;
                if(pos < BINCAP)
                    earena[(size_t)bin*BINCAP + pos] =
                        ((unsigned)(s&63)<<11) | (unsigned)(d&2047);
            }
        }
    }
}

// ---- Kernel 3: LDS adjacency rebuild + aggregation + hout GEMM + heads -----
// grid 512 (64 nodes each = bucket blockIdx). 4 waves. Register prefetch on
// edge words and all GEMM B tiles (loads overlap ballot/popcount/MFMA VALU).
__global__ __launch_bounds__(256) void msg3_k(
    const int* __restrict__ ids, const unsigned* __restrict__ ecnt,
    const unsigned* __restrict__ earena, const float* __restrict__ embed,
    const short* __restrict__ wmth, const short* __restrict__ wmtl,
    const float* __restrict__ b_msg, const float* __restrict__ w_coor,
    const short* __restrict__ a1th, const short* __restrict__ a1tl,
    const float* __restrict__ a1v, const float* __restrict__ A2,
    const float* __restrict__ a2v, const float* __restrict__ dalpha,
    const float* __restrict__ dw, const float* __restrict__ db,
    const float* __restrict__ coords, float* __restrict__ out_ang,
    float* __restrict__ out_z, float* __restrict__ out_co)
{
    __shared__ unsigned short v_bf[64*136];    // v bf16 (row pad 136)
    __shared__ unsigned short houts[64*136];   // hout bf16; later t1s [64][104]
    // arena phase 0/1: lmask u32[4096] | ind u32[1280] | sid u8[2048] | emb f32[2560]
    // GEMM phases:     sBh[10240 B] | sBl[10240 B] (overlays lmask+ind)
    __shared__ __align__(16) unsigned char arena[33792];
    __shared__ float s_bm[128], s_wc[384], s_A2[624], s_a1[104];
    __shared__ float s_dyt[16], s_a2[8];

    unsigned*       lmask = (unsigned*)arena;
    unsigned*       ind   = (unsigned*)(arena + 16384);
    unsigned char*  sid   = arena + 21504;
    float*          emb   = (float*)(arena + 23552);
    short*          sBh   = (short*)arena;
    short*          sBl   = (short*)(arena + 10240);

    int tid = threadIdx.x;
    int bin = blockIdx.x;
    int row0 = bin*64;
    int g = blockIdx.x>>5, tile = blockIdx.x&31;
    int lane = tid&63, w = tid>>6;
    int ln = lane&15, quad = lane>>4;
    int m0w = (w&1)*32, n0w = (w>>1)*64;

    // --- phase 0: constants + emb + sid + zero lmask ------------------------
    int nb = min((int)ecnt[bin], BINCAP);
    for(int l=tid;l<NATOMS*128;l+=256) emb[l] = embed[l];
    #pragma unroll
    for(int i=0;i<8;i++){ int j = tid + i*256; sid[j] = (unsigned char)ids[g*Nn + j]; }
    #pragma unroll
    for(int i=0;i<16;i++) lmask[tid + i*256] = 0;
    if(tid<128) s_bm[tid] = b_msg[tid];
    if(tid<104) s_a1[tid] = (tid<ENCH) ? a1v[tid] : 0.f;
    for(int l=tid;l<384;l+=256) s_wc[l] = w_coor[l];
    for(int l=tid;l<624;l+=256) s_A2[l] = (l<600) ? A2[l] : 0.f;
    if(tid==0)  s_dyt[0] = dalpha[0];
    if(tid<6){ s_dyt[1+tid] = dw[tid]; s_dyt[8+tid] = db[tid]; }
    if(tid<8)  s_a2[tid] = (tid<6) ? a2v[tid] : 0.f;
    __syncthreads();

    // --- phase 1: edge-word loads issued FIRST (overlap the ballot VALU) ----
    unsigned ew[12]; int ne = 0;
    #pragma unroll
    for(int j=0;j<12;j++){
        int i = tid + j*256;
        if(i < nb){ ew[j] = earena[(size_t)bin*BINCAP + i]; ne = j+1; }
    }
    for(int wp=w; wp<32; wp+=4){               // ballot indicator bitmasks
        int a = sid[wp*64 + lane];
        #pragma unroll
        for(int atom=0; atom<NATOMS; atom++){
            unsigned long long bm = __ballot(a==atom);
            if(lane<2) ind[atom*64 + wp*2 + lane] = (unsigned)(bm >> (32*lane));
        }
    }
    for(int j=0;j<ne;j++){                     // apply edges to LDS adjacency
        unsigned wv = ew[j];
        int sl = wv>>11, dl = wv & 2047;
        atomicOr(&lmask[sl*64 + (dl>>5)], 1u<<(dl&31));
    }
    __syncthreads();

    // --- phase 2: per-node counts popcount(lmask & ind), 4-lane split -------
    // (W_msg tile-0 loads issued up front; consumed after the v barrier)
    bf16x8 wbm[4];
    #pragma unroll
    for(int i=0;i<4;i++){ int id=tid+i*256; int plane=id>>9,cid=id&511;
        int r=cid>>2,c=cid&3;
        wbm[i] = *(const bf16x8*)((plane? wmtl:wmth) + (size_t)r*128 + c*8); }
    int node = tid>>2, p = tid&3;
    unsigned mw[16];
    {
        const unsigned* mrow = &lmask[node*64 + p*16];
        *(uint4*)&mw[0]  = *(const uint4*)&mrow[0];
        *(uint4*)&mw[4]  = *(const uint4*)&mrow[4];
        *(uint4*)&mw[8]  = *(const uint4*)&mrow[8];
        *(uint4*)&mw[12] = *(const uint4*)&mrow[12];
    }
    int degi = 0;
    #pragma unroll
    for(int w2=0;w2<16;w2++) degi += __popc(mw[w2]);
    float cnt[NATOMS];
    #pragma unroll
    for(int a=0;a<NATOMS;a++){
        int c = 0;
        const unsigned* ia = &ind[a*64 + p*16];
        #pragma unroll
        for(int w2=0;w2<16;w2++) c += __popc(mw[w2] & ia[w2]);
        cnt[a] = (float)c;
    }
    #pragma unroll
    for(int a=0;a<NATOMS;a++){
        cnt[a] += __shfl_xor(cnt[a],1,64);
        cnt[a] += __shfl_xor(cnt[a],2,64);
    }
    float deg = (float)degi;
    deg += __shfl_xor(deg,1,64);
    deg += __shfl_xor(deg,2,64);

    // --- v = emb[own] + (sum_a cnt_a emb_a)/max(deg,1) -> LDS bf16 ----------
    {
        float inv = 1.0f / fmaxf(deg, 1.0f);
        int oid = sid[tile*64 + node];
        int d0 = p*32;
        float vv[32];
        #pragma unroll
        for(int d=0;d<32;d++) vv[d]=0.f;
        #pragma unroll
        for(int a=0;a<NATOMS;a++){
            float ca = cnt[a];
            const float* ea = &emb[a*128 + d0];
            #pragma unroll
            for(int d=0;d<32;d+=4){
                float4 e = *(const float4*)&ea[d];
                vv[d]+=ca*e.x; vv[d+1]+=ca*e.y; vv[d+2]+=ca*e.z; vv[d+3]+=ca*e.w;
            }
        }
        const float* eo = &emb[oid*128 + d0];
        unsigned short* dst = &v_bf[node*136 + d0];
        #pragma unroll
        for(int d=0;d<32;d+=4){
            float4 e = *(const float4*)&eo[d];
            ushort4 o;
            o.x = f2b(e.x + vv[d]*inv);
            o.y = f2b(e.y + vv[d+1]*inv);
            o.z = f2b(e.z + vv[d+2]*inv);
            o.w = f2b(e.w + vv[d+3]*inv);
            *(ushort4*)&dst[d] = o;
        }
    }
    __syncthreads();     // v complete; lmask/ind/sid/emb dead -> arena = sB

    // ---- hout = gelu(v @ W_msg + b), 2-term W split, depth-1 prefetch ------
    f32x4 acc[2][4];
    #pragma unroll
    for(int i=0;i<2;i++)
        #pragma unroll
        for(int j=0;j<4;j++) acc[i][j] = (f32x4){0.f,0.f,0.f,0.f};
    for(int k0=0;k0<128;k0+=32){
        #pragma unroll
        for(int i=0;i<4;i++){                           // B regs -> LDS
            int id = tid + i*256; int plane = id>>9, cid = id&511;
            int r = cid>>2, c = cid&3;
            *(bf16x8*)((plane? sBl : sBh) + r*40 + c*8) = wbm[i];
        }
        __syncthreads();
        if(k0 < 96){                                    // prefetch next tile
            #pragma unroll
            for(int i=0;i<4;i++){ int id=tid+i*256; int plane=id>>9,cid=id&511;
                int r=cid>>2,c=cid&3;
                wbm[i] = *(const bf16x8*)((plane? wmtl:wmth)
                          + (size_t)r*128 + k0+32 + c*8); }
        }
        bf16x8 av[2];
        #pragma unroll
        for(int tm=0;tm<2;tm++)
            av[tm] = *(const bf16x8*)&v_bf[(m0w+tm*16+ln)*136 + k0 + quad*8];
        #pragma unroll
        for(int tn=0;tn<4;tn++){
            bf16x8 bh = *(const bf16x8*)&sBh[(n0w+tn*16+ln)*40 + quad*8];
            bf16x8 bl = *(const bf16x8*)&sBl[(n0w+tn*16+ln)*40 + quad*8];
            #pragma unroll
            for(int tm=0;tm<2;tm++){
                acc[tm][tn] = __builtin_amdgcn_mfma_f32_16x16x32_bf16(av[tm], bl, acc[tm][tn], 0,0,0);
                acc[tm][tn] = __builtin_amdgcn_mfma_f32_16x16x32_bf16(av[tm], bh, acc[tm][tn], 0,0,0);
            }
        }
        __syncthreads();
    }
    // epilogue: z fp32 + hout bf16 to LDS; A1 tile-0 loads issued here -------
    bf16x8 wa[4];
    #pragma unroll
    for(int i=0;i<4;i++){ int id=tid+i*256; int plane=id>>9,cid=id&511;
        int r=cid>>2,c=cid&3;
        wa[i] = *(const bf16x8*)((plane? a1tl:a1th) + (size_t)r*128 + c*8); }
    #pragma unroll
    for(int tn=0;tn<4;tn++){
        int col = n0w + tn*16 + ln;
        float bias = s_bm[col];
        #pragma unroll
        for(int tm=0;tm<2;tm++){
            int mb2 = m0w + tm*16 + quad*4;
            #pragma unroll
            for(int r=0;r<4;r++){
                float hv = gelu_f(acc[tm][tn][r] + bias);
                out_z[(size_t)(row0+mb2+r)*128 + col] = hv;
                houts[(mb2+r)*136 + col] = f2b(hv);
            }
        }
    }
    __syncthreads();

    // ---- coors: 4-lane k-split dot with w_coor -----------------------------
    {
        float d0=0.f, d1=0.f, d2=0.f;
        int kb = p*32;
        #pragma unroll
        for(int k=0;k<32;k+=4){
            ushort4 hv = *(const ushort4*)&houts[node*136 + kb + k];
            float h0=b2f(hv.x),h1=b2f(hv.y),h2=b2f(hv.z),h3=b2f(hv.w);
            const float* wc = &s_wc[(kb+k)*3];
            d0 += h0*wc[0]+h1*wc[3]+h2*wc[6]+h3*wc[9];
            d1 += h0*wc[1]+h1*wc[4]+h2*wc[7]+h3*wc[10];
            d2 += h0*wc[2]+h1*wc[5]+h2*wc[8]+h3*wc[11];
        }
        d0 += __shfl_xor(d0,1,64); d0 += __shfl_xor(d0,2,64);
        d1 += __shfl_xor(d1,1,64); d1 += __shfl_xor(d1,2,64);
        d2 += __shfl_xor(d2,1,64); d2 += __shfl_xor(d2,2,64);
        if(p==0){
            size_t o = (size_t)(row0+node)*3;
            out_co[o+0] = coords[o+0] + tanhf(d0);
            out_co[o+1] = coords[o+1] + tanhf(d1);
            out_co[o+2] = coords[o+2] + tanhf(d2);
        }
    }

    // ---- t1 = gelu(hout @ A1 + a1), 2-term split, depth-1 prefetch ---------
    f32x4 acc2[2][4];
    #pragma unroll
    for(int i=0;i<2;i++)
        #pragma unroll
        for(int j=0;j<4;j++) acc2[i][j] = (f32x4){0.f,0.f,0.f,0.f};
    for(int k0=0;k0<128;k0+=32){
        __syncthreads();                    // protect sB reuse across iters
        #pragma unroll
        for(int i=0;i<4;i++){
            int id = tid + i*256; int plane = id>>9, cid = id&511;
            int r = cid>>2, c = cid&3;
            *(bf16x8*)((plane? sBl : sBh) + r*40 + c*8) = wa[i];
        }
        __syncthreads();
        if(k0 < 96){
            #pragma unroll
            for(int i=0;i<4;i++){ int id=tid+i*256; int plane=id>>9,cid=id&511;
                int r=cid>>2,c=cid&3;
                wa[i] = *(const bf16x8*)((plane? a1tl:a1th)
                          + (size_t)r*128 + k0+32 + c*8); }
        }
        bf16x8 ah[2];
        #pragma unroll
        for(int tm=0;tm<2;tm++)
            ah[tm] = *(const bf16x8*)&houts[(m0w+tm*16+ln)*136 + k0 + quad*8];
        #pragma unroll
        for(int tn=0;tn<4;tn++){
            bf16x8 bh = *(const bf16x8*)&sBh[(n0w+tn*16+ln)*40 + quad*8];
            bf16x8 bl = *(const bf16x8*)&sBl[(n0w+tn*16+ln)*40 + quad*8];
            #pragma unroll
            for(int tm=0;tm<2;tm++){
                acc2[tm][tn] = __builtin_amdgcn_mfma_f32_16x16x32_bf16(ah[tm], bl, acc2[tm][tn], 0,0,0);
                acc2[tm][tn] = __builtin_amdgcn_mfma_f32_16x16x32_bf16(ah[tm], bh, acc2[tm][tn], 0,0,0);
            }
        }
    }
    __syncthreads();                        // houts reads done -> reuse as t1s
    unsigned short* t1s = houts;            // [64][104]
    #pragma unroll
    for(int tn=0;tn<4;tn++){
        int col = n0w + tn*16 + ln;
        if(col < 104){
            float bias = s_a1[col];
            #pragma unroll
            for(int tm=0;tm<2;tm++){
                int mb2 = m0w + tm*16 + quad*4;
                #pragma unroll
                for(int r=0;r<4;r++)
                    t1s[(mb2+r)*104 + col] = f2b(gelu_f(acc2[tm][tn][r] + bias));
            }
        }
    }
    __syncthreads();

    // ---- t2 = gelu(t1@A2+a2); DyT; angles ----------------------------------
    {
        int g0 = (p<2) ? p*7 : 14+(p-2)*6;
        int gcount = (p<2) ? 7 : 6;
        float s[6] = {0.f,0.f,0.f,0.f,0.f,0.f};
        for(int gg=0; gg<gcount; gg++){
            int kb = (g0+gg)*4;
            ushort4 tv = *(const ushort4*)&t1s[node*104 + kb];
            float u0=b2f(tv.x), u1=b2f(tv.y), u2=b2f(tv.z), u3=b2f(tv.w);
            #pragma unroll
            for(int j=0;j<6;j++)
                s[j] += u0*s_A2[kb*6+j] + u1*s_A2[(kb+1)*6+j]
                      + u2*s_A2[(kb+2)*6+j] + u3*s_A2[(kb+3)*6+j];
        }
        #pragma unroll
        for(int j=0;j<6;j++){ s[j]+=__shfl_xor(s[j],1,64); s[j]+=__shfl_xor(s[j],2,64); }
        if(p<2){
            size_t o = (size_t)(row0+node)*6 + p*3;
            #pragma unroll
            for(int jj=0;jj<3;jj++){
                int j = p*3+jj;
                float t2v = gelu_f(s[j] + s_a2[j]);
                float uu = tanhf(s_dyt[0]*t2v)*s_dyt[1+j] + s_dyt[8+j];
                out_ang[o+jj] = tanhf(uu);
            }
        }
    }
}

// ---------------------------------------------------------------------------
extern "C" void kernel_launch(void* const* d_in, const int* in_sizes, int n_in,
                              void* d_out, int out_size, void* d_ws, size_t ws_size,
                              hipStream_t stream) {
    const float* x      = (const float*)d_in[0];
    const float* coords = (const float*)d_in[1];
    const int*   ei     = (const int*)d_in[2];
    const float* gamma  = (const float*)d_in[4];
    const float* beta   = (const float*)d_in[5];
    const float* W1     = (const float*)d_in[6];
    const float* b1     = (const float*)d_in[7];
    const float* W2     = (const float*)d_in[8];
    const float* b2     = (const float*)d_in[9];
    const float* W3     = (const float*)d_in[10];
    const float* b3     = (const float*)d_in[11];
    const float* embed  = (const float*)d_in[12];
    const float* W_msg  = (const float*)d_in[13];
    const float* b_msg  = (const float*)d_in[14];
    const float* w_coor = (const float*)d_in[15];
    const float* A1     = (const float*)d_in[16];
    const float* a1v    = (const float*)d_in[17];
    const float* A2     = (const float*)d_in[18];
    const float* a2v    = (const float*)d_in[19];
    const float* dalpha = (const float*)d_in[20];
    const float* dw     = (const float*)d_in[21];
    const float* db     = (const float*)d_in[22];

    // ws layout (~7.3 MB peak):
    //  0      : ids   (128 KB)
    //  128K   : stats (2 KB) + ecnt (2 KB)   <- one 4 KB memset
    //  256K   : weight planes (512 KB)
    //  1M     : earena u32[512*3072] (6 MB)
    char* ws = (char*)d_ws;
    int*      ids   = (int*)ws;
    float*    stats = (float*)(ws + 131072);
    unsigned* ecnt  = (unsigned*)(ws + 131072 + 2048);
    short*    w1th  = (short*)(ws + 262144);
    short*    w1tl  = w1th + 65536;
    short*    w2th  = w1tl + 65536;
    short*    w2tl  = w2th + 32768;
    short*    wmth  = w2tl + 32768;
    short*    wmtl  = wmth + 16384;
    short*    a1th  = wmtl + 16384;
    short*    a1tl  = a1th + 16384;
    unsigned* earena = (unsigned*)(ws + (1<<20));

    float* out_ang = (float*)d_out;
    float* out_z   = out_ang + (size_t)NT*OUTC;
    float* out_co  = out_z   + (size_t)NT*DIMd;

    hipMemsetAsync(stats, 0, 4096, stream);      // stats + ecnt
    prep0_k<<<288, 256, 0, stream>>>(x, stats, W1, W2, W_msg, A1,
        w1th, w1tl, w2th, w2tl, wmth, wmtl, a1th, a1tl);
    gemm123_k<<<512, 256, 0, stream>>>(x, stats, gamma, beta, w1th, w1tl, b1,
        w2th, w2tl, b2, W3, b3, ids, ei, ecnt, earena);
    msg3_k<<<512, 256, 0, stream>>>(ids, ecnt, earena, embed, wmth, wmtl, b_msg,
        w_coor, a1th, a1tl, a1v, A2, a2v, dalpha, dw, db, coords,
        out_ang, out_z, out_co);
}

// Round 10
// 260.840 us; speedup vs baseline: 1.2171x; 1.0016x over previous
//
#include <hip/hip_runtime.h>
#include <hip/hip_cooperative_groups.h>
#include <hip/hip_bf16.h>
#include <math.h>

namespace cg = cooperative_groups;

// Problem constants (match reference)
#define Bg 16
#define Nn 2048
#define Ee (1<<20)
#define NT (Bg*Nn)
#define INC 256
#define DIMd 128
#define OUTC 6
#define ENCH 100
#define NATOMS 20
#define BINCAP 3072   // per-bin edge capacity: mean 2048, sigma~44 -> +23 sigma

typedef __attribute__((ext_vector_type(8))) short bf16x8;
typedef __attribute__((ext_vector_type(4))) float f32x4;

__device__ __forceinline__ float gelu_f(float x){
    return 0.5f*x*(1.0f+erff(x*0.70710678118654752440f));
}
__device__ __forceinline__ unsigned short f2b(float f){
    __hip_bfloat16 h = __float2bfloat16(f);
    return *(unsigned short*)&h;
}
__device__ __forceinline__ float b2f(unsigned short u){
    unsigned v = ((unsigned)u)<<16;
    return __uint_as_float(v);
}
// split fp32 into bf16 hi + bf16 lo (v ~= hi + lo, dropped residual ~2^-18 rel)
__device__ __forceinline__ void splitf(float v, unsigned short& hi, unsigned short& lo){
    unsigned short h = f2b(v);
    hi = h; lo = f2b(v - b2f(h));
}

// ===========================================================================
// FALLBACK PATH (R8, known-good): prep0_k + gemm123_k + msg3_k
// ===========================================================================

__global__ __launch_bounds__(256) void prep0_k(const float* __restrict__ x,
    float* __restrict__ stats, const float* __restrict__ W1,
    const float* __restrict__ W2, const float* __restrict__ Wm,
    const float* __restrict__ A1, short* __restrict__ w1th, short* __restrict__ w1tl,
    short* __restrict__ w2th, short* __restrict__ w2tl,
    short* __restrict__ wmth, short* __restrict__ wmtl,
    short* __restrict__ a1th, short* __restrict__ a1tl)
{
    __shared__ float st[64*65];
    int bx = blockIdx.x, tid = threadIdx.x;
    if(bx < 256){
        int c = tid;
        int r0 = bx * 128;
        const float* p = x + (size_t)r0*INC + c;
        float s = 0.f, s2 = 0.f;
        #pragma unroll 8
        for(int r=0;r<128;r++){ float v = p[(size_t)r*INC]; s += v; s2 += v*v; }
        atomicAdd(&stats[c], s);
        atomicAdd(&stats[INC+c], s2);
        return;
    }
    int t = bx - 256;
    const float* src; short *dh, *dl;
    int k0, n0, lds, ldd, nmax;
    if(t < 16){        src=W1; dh=w1th; dl=w1tl; lds=256; ldd=256; nmax=256;
                       k0=(t>>2)*64;      n0=(t&3)*64; }
    else if(t < 24){   int u=t-16; src=W2; dh=w2th; dl=w2tl; lds=128; ldd=256; nmax=128;
                       k0=(u>>1)*64;      n0=(u&1)*64; }
    else if(t < 28){   int u=t-24; src=Wm; dh=wmth; dl=wmtl; lds=128; ldd=128; nmax=128;
                       k0=(u>>1)*64;      n0=(u&1)*64; }
    else {             int u=t-28; src=A1; dh=a1th; dl=a1tl; lds=100; ldd=128; nmax=100;
                       k0=(u>>1)*64;      n0=(u&1)*64; }
    #pragma unroll
    for(int i=0;i<16;i++){
        int idx = tid + i*256; int r = idx>>6, c = idx&63;
        float v = (n0+c < nmax) ? src[(size_t)(k0+r)*lds + n0+c] : 0.f;
        st[r*65+c] = v;
    }
    __syncthreads();
    #pragma unroll
    for(int i=0;i<16;i++){
        int idx = tid + i*256; int rr = idx>>6, cc = idx&63;
        unsigned short hi, lo;
        splitf(st[cc*65+rr], hi, lo);
        size_t o = (size_t)(n0+rr)*ldd + k0+cc;
        dh[o] = (short)hi; dl[o] = (short)lo;
    }
}

__global__ __launch_bounds__(256) void gemm123_k(const float* __restrict__ x,
    const float* __restrict__ stats, const float* __restrict__ gamma,
    const float* __restrict__ beta, const short* __restrict__ w1th,
    const short* __restrict__ w1tl, const float* __restrict__ b1,
    const short* __restrict__ w2th, const short* __restrict__ w2tl,
    const float* __restrict__ b2, const float* __restrict__ W3,
    const float* __restrict__ b3, int* __restrict__ ids,
    const int* __restrict__ ei, unsigned* __restrict__ ecnt,
    unsigned* __restrict__ earena)
{
    __shared__ float sc[256], sh[256];
    __shared__ __align__(16) unsigned char smem[51200];
    short* sAh = (short*)smem;
    short* sAl = sAh + 64*40;
    short* sBh = (short*)(smem + 10240);
    short* sBl = sBh + 256*40;
    float* h2s = (float*)(smem + 10240);
    float* lgs = (float*)(smem + 44032);
    float* w3s = (float*)smem;

    int tid = threadIdx.x;
    {
        float mu  = stats[tid]*(1.0f/NT);
        float var = stats[256+tid]*(1.0f/NT) - mu*mu;
        float s = gamma[tid]/sqrtf(var + 1e-5f);
        sc[tid] = s; sh[tid] = beta[tid] - mu*s;
    }
    int row0 = blockIdx.x*64;
    int lane = tid&63, w = tid>>6;
    int ln = lane&15, quad = lane>>4;
    int m0w = (w&1)*32, nb1 = (w>>1)*128, nb2 = (w>>1)*64;

    f32x4 acc[2][8];
    #pragma unroll
    for(int i=0;i<2;i++)
        #pragma unroll
        for(int j=0;j<8;j++) acc[i][j] = (f32x4){0.f,0.f,0.f,0.f};
    float bias1[8];
    #pragma unroll
    for(int tn=0;tn<8;tn++) bias1[tn] = b1[nb1 + tn*16 + ln];

    float4 xa[2][2]; bf16x8 wb[2][8];
    #pragma unroll
    for(int t=0;t<2;t++){
        #pragma unroll
        for(int i=0;i<2;i++){ int id=tid+i*256; int r=id>>3,kq=(id&7)*4;
            xa[t][i] = *(const float4*)&x[(size_t)(row0+r)*256 + t*32 + kq]; }
        #pragma unroll
        for(int i=0;i<8;i++){ int id=tid+i*256; int plane=id>>10,cid=id&1023;
            int r=cid>>2,c=cid&3;
            wb[t][i] = *(const bf16x8*)((plane? w1tl:w1th) + (size_t)r*256 + t*32 + c*8); }
    }
    __syncthreads();
    for(int k0=0;k0<256;k0+=32){
        int cur = (k0>>5)&1;
        #pragma unroll
        for(int i=0;i<2;i++){
            int id = tid + i*256; int r = id>>3, kq = (id&7)*4;
            int k = k0+kq;
            float v0 = xa[cur][i].x*sc[k]+sh[k],     v1 = xa[cur][i].y*sc[k+1]+sh[k+1];
            float v2 = xa[cur][i].z*sc[k+2]+sh[k+2], v3 = xa[cur][i].w*sc[k+3]+sh[k+3];
            ushort4 hi, lo;
            splitf(v0,hi.x,lo.x); splitf(v1,hi.y,lo.y);
            splitf(v2,hi.z,lo.z); splitf(v3,hi.w,lo.w);
            *(ushort4*)&sAh[r*40+kq] = hi;
            *(ushort4*)&sAl[r*40+kq] = lo;
        }
        #pragma unroll
        for(int i=0;i<8;i++){
            int id = tid + i*256; int plane = id>>10, cid = id&1023;
            int r = cid>>2, c = cid&3;
            *(bf16x8*)((plane? sBl : sBh) + r*40 + c*8) = wb[cur][i];
        }
        __syncthreads();
        if(k0 < 192){
            #pragma unroll
            for(int i=0;i<2;i++){ int id=tid+i*256; int r=id>>3,kq=(id&7)*4;
                xa[cur][i] = *(const float4*)&x[(size_t)(row0+r)*256 + k0+64+kq]; }
            #pragma unroll
            for(int i=0;i<8;i++){ int id=tid+i*256; int plane=id>>10,cid=id&1023;
                int r=cid>>2,c=cid&3;
                wb[cur][i] = *(const bf16x8*)((plane? w1tl:w1th) + (size_t)r*256 + k0+64 + c*8); }
        }
        bf16x8 ah[2], al[2];
        #pragma unroll
        for(int tm=0;tm<2;tm++){
            ah[tm] = *(const bf16x8*)&sAh[(m0w+tm*16+ln)*40 + quad*8];
            al[tm] = *(const bf16x8*)&sAl[(m0w+tm*16+ln)*40 + quad*8];
        }
        #pragma unroll
        for(int tn=0;tn<8;tn++){
            bf16x8 bh = *(const bf16x8*)&sBh[(nb1+tn*16+ln)*40 + quad*8];
            bf16x8 bl = *(const bf16x8*)&sBl[(nb1+tn*16+ln)*40 + quad*8];
            #pragma unroll
            for(int tm=0;tm<2;tm++){
                acc[tm][tn] = __builtin_amdgcn_mfma_f32_16x16x32_bf16(al[tm], bh, acc[tm][tn], 0,0,0);
                acc[tm][tn] = __builtin_amdgcn_mfma_f32_16x16x32_bf16(ah[tm], bl, acc[tm][tn], 0,0,0);
                acc[tm][tn] = __builtin_amdgcn_mfma_f32_16x16x32_bf16(ah[tm], bh, acc[tm][tn], 0,0,0);
            }
        }
        __syncthreads();
    }

    f32x4 acc2[2][4];
    #pragma unroll
    for(int i=0;i<2;i++)
        #pragma unroll
        for(int j=0;j<4;j++) acc2[i][j] = (f32x4){0.f,0.f,0.f,0.f};
    bf16x8 wb2[4];
    #pragma unroll
    for(int i=0;i<4;i++){ int id=tid+i*256; int plane=id>>9,cid=id&511;
        int r=cid>>2,c=cid&3;
        wb2[i] = *(const bf16x8*)((plane? w2tl:w2th) + (size_t)r*256 + c*8); }
    #pragma unroll
    for(int cc=0;cc<8;cc++){
        if((w>>1) == (cc>>2)){
            int clp = cc&3;
            #pragma unroll
            for(int t=0;t<2;t++){
                int tn = 2*clp + t;
                #pragma unroll
                for(int tm=0;tm<2;tm++){
                    #pragma unroll
                    for(int r=0;r<4;r++){
                        int row = m0w + tm*16 + quad*4 + r;
                        float hv = gelu_f(acc[tm][tn][r] + bias1[tn]);
                        unsigned short hi, lo;
                        splitf(hv, hi, lo);
                        sAh[row*40 + t*16 + ln] = (short)hi;
                        sAl[row*40 + t*16 + ln] = (short)lo;
                    }
                }
            }
        }
        #pragma unroll
        for(int i=0;i<4;i++){
            int id = tid + i*256; int plane = id>>9, cid = id&511;
            int r = cid>>2, c = cid&3;
            *(bf16x8*)((plane? sBl : sBh) + r*40 + c*8) = wb2[i];
        }
        __syncthreads();
        if(cc < 7){
            #pragma unroll
            for(int i=0;i<4;i++){ int id=tid+i*256; int plane=id>>9,cid=id&511;
                int r=cid>>2,c=cid&3;
                wb2[i] = *(const bf16x8*)((plane? w2tl:w2th)
                          + (size_t)r*256 + (cc+1)*32 + c*8); }
        }
        bf16x8 ah[2], al[2];
        #pragma unroll
        for(int tm=0;tm<2;tm++){
            ah[tm] = *(const bf16x8*)&sAh[(m0w+tm*16+ln)*40 + quad*8];
            al[tm] = *(const bf16x8*)&sAl[(m0w+tm*16+ln)*40 + quad*8];
        }
        #pragma unroll
        for(int tn=0;tn<4;tn++){
            bf16x8 bh = *(const bf16x8*)&sBh[(nb2+tn*16+ln)*40 + quad*8];
            bf16x8 bl = *(const bf16x8*)&sBl[(nb2+tn*16+ln)*40 + quad*8];
            #pragma unroll
            for(int tm=0;tm<2;tm++){
                acc2[tm][tn] = __builtin_amdgcn_mfma_f32_16x16x32_bf16(al[tm], bh, acc2[tm][tn], 0,0,0);
                acc2[tm][tn] = __builtin_amdgcn_mfma_f32_16x16x32_bf16(ah[tm], bl, acc2[tm][tn], 0,0,0);
                acc2[tm][tn] = __builtin_amdgcn_mfma_f32_16x16x32_bf16(ah[tm], bh, acc2[tm][tn], 0,0,0);
            }
        }
        __syncthreads();
    }

    #pragma unroll
    for(int tn=0;tn<4;tn++){
        int col = nb2 + tn*16 + ln;
        float bias = b2[col];
        #pragma unroll
        for(int tm=0;tm<2;tm++){
            int rb = m0w + tm*16 + quad*4;
            #pragma unroll
            for(int r=0;r<4;r++)
                h2s[(rb+r)*132 + col] = gelu_f(acc2[tm][tn][r] + bias);
        }
    }
    for(int l=tid;l<2560;l+=256) w3s[l] = W3[l];
    __syncthreads();
    {
        int n = tid>>2, q = tid&3;
        float lg[5] = {};
        #pragma unroll 4
        for(int k=0;k<128;k++){
            float h = h2s[n*132+k];
            #pragma unroll
            for(int a=0;a<5;a++) lg[a] += h*w3s[k*20 + q*5 + a];
        }
        #pragma unroll
        for(int a=0;a<5;a++) lgs[n*20 + q*5 + a] = lg[a] + b3[q*5+a];
    }
    __syncthreads();
    if(tid<64){
        float best = lgs[tid*20]; int bi = 0;
        #pragma unroll
        for(int a=1;a<20;a++){ float v2 = lgs[tid*20+a]; if(v2>best){best=v2;bi=a;} }
        ids[row0+tid] = bi;
    }

    if(blockIdx.x < 256){
        __syncthreads();
        unsigned* lcnt  = (unsigned*)sAh;
        unsigned* gbase = ((unsigned*)sAh) + 512;
        for(int l=tid; l<512; l+=256) lcnt[l] = 0;
        __syncthreads();
        int ebase = blockIdx.x * 4096;
        #pragma unroll 4
        for(int i=0;i<16;i++){
            int e = ebase + i*256 + tid;
            int s = ei[e], d = ei[Ee+e];
            if((s>>11)==(d>>11)) atomicAdd(&lcnt[s>>6], 1u);
        }
        __syncthreads();
        for(int l=tid; l<512; l+=256){
            unsigned c = lcnt[l];
            gbase[l] = c ? atomicAdd(&ecnt[l], c) : 0u;
            lcnt[l] = 0;
        }
        __syncthreads();
        #pragma unroll 4
        for(int i=0;i<16;i++){
            int e = ebase + i*256 + tid;
            int s = ei[e], d = ei[Ee+e];
            if((s>>11)==(d>>11)){
                int bin = s>>6;
                unsigned r = atomicAdd(&lcnt[bin], 1u);
                unsigned pos = gbase[bin] + r;
                if(pos < BINCAP)
                    earena[(size_t)bin*BINCAP + pos] =
                        ((unsigned)(s&63)<<11) | (unsigned)(d&2047);
            }
        }
    }
}

__global__ __launch_bounds__(256) void msg3_k(
    const int* __restrict__ ids, const unsigned* __restrict__ ecnt,
    const unsigned* __restrict__ earena, const float* __restrict__ embed,
    const short* __restrict__ wmth, const short* __restrict__ wmtl,
    const float* __restrict__ b_msg, const float* __restrict__ w_coor,
    const short* __restrict__ a1th, const short* __restrict__ a1tl,
    const float* __restrict__ a1v, const float* __restrict__ A2,
    const float* __restrict__ a2v, const float* __restrict__ dalpha,
    const float* __restrict__ dw, const float* __restrict__ db,
    const float* __restrict__ coords, float* __restrict__ out_ang,
    float* __restrict__ out_z, float* __restrict__ out_co)
{
    __shared__ unsigned short v_bf[64*136];
    __shared__ unsigned short houts[64*136];
    __shared__ __align__(16) unsigned char arena[33792];
    __shared__ float s_bm[128], s_wc[384], s_A2[624], s_a1[104];
    __shared__ float s_dyt[16], s_a2[8];

    unsigned*       lmask = (unsigned*)arena;
    unsigned*       ind   = (unsigned*)(arena + 16384);
    unsigned char*  sid   = arena + 21504;
    float*          emb   = (float*)(arena + 23552);
    short*          sBh   = (short*)arena;
    short*          sBl   = (short*)(arena + 10240);

    int tid = threadIdx.x;
    int bin = blockIdx.x;
    int row0 = bin*64;
    int g = blockIdx.x>>5, tile = blockIdx.x&31;
    int lane = tid&63, w = tid>>6;
    int ln = lane&15, quad = lane>>4;
    int m0w = (w&1)*32, n0w = (w>>1)*64;

    int nbin = min((int)ecnt[bin], BINCAP);
    for(int l=tid;l<NATOMS*128;l+=256) emb[l] = embed[l];
    #pragma unroll
    for(int i=0;i<8;i++){ int j = tid + i*256; sid[j] = (unsigned char)ids[g*Nn + j]; }
    #pragma unroll
    for(int i=0;i<16;i++) lmask[tid + i*256] = 0;
    if(tid<128) s_bm[tid] = b_msg[tid];
    if(tid<104) s_a1[tid] = (tid<ENCH) ? a1v[tid] : 0.f;
    for(int l=tid;l<384;l+=256) s_wc[l] = w_coor[l];
    for(int l=tid;l<624;l+=256) s_A2[l] = (l<600) ? A2[l] : 0.f;
    if(tid==0)  s_dyt[0] = dalpha[0];
    if(tid<6){ s_dyt[1+tid] = dw[tid]; s_dyt[8+tid] = db[tid]; }
    if(tid<8)  s_a2[tid] = (tid<6) ? a2v[tid] : 0.f;
    __syncthreads();

    unsigned ew[12]; int ne = 0;
    #pragma unroll
    for(int j=0;j<12;j++){
        int i = tid + j*256;
        if(i < nbin){ ew[j] = earena[(size_t)bin*BINCAP + i]; ne = j+1; }
    }
    for(int wp=w; wp<32; wp+=4){
        int a = sid[wp*64 + lane];
        #pragma unroll
        for(int atom=0; atom<NATOMS; atom++){
            unsigned long long bm = __ballot(a==atom);
            if(lane<2) ind[atom*64 + wp*2 + lane] = (unsigned)(bm >> (32*lane));
        }
    }
    for(int j=0;j<ne;j++){
        unsigned wv = ew[j];
        int sl = wv>>11, dl = wv & 2047;
        atomicOr(&lmask[sl*64 + (dl>>5)], 1u<<(dl&31));
    }
    __syncthreads();

    bf16x8 wbm[4];
    #pragma unroll
    for(int i=0;i<4;i++){ int id=tid+i*256; int plane=id>>9,cid=id&511;
        int r=cid>>2,c=cid&3;
        wbm[i] = *(const bf16x8*)((plane? wmtl:wmth) + (size_t)r*128 + c*8); }
    int node = tid>>2, p = tid&3;
    unsigned mw[16];
    {
        const unsigned* mrow = &lmask[node*64 + p*16];
        *(uint4*)&mw[0]  = *(const uint4*)&mrow[0];
        *(uint4*)&mw[4]  = *(const uint4*)&mrow[4];
        *(uint4*)&mw[8]  = *(const uint4*)&mrow[8];
        *(uint4*)&mw[12] = *(const uint4*)&mrow[12];
    }
    int degi = 0;
    #pragma unroll
    for(int w2=0;w2<16;w2++) degi += __popc(mw[w2]);
    float cnt[NATOMS];
    #pragma unroll
    for(int a=0;a<NATOMS;a++){
        int c = 0;
        const unsigned* ia = &ind[a*64 + p*16];
        #pragma unroll
        for(int w2=0;w2<16;w2++) c += __popc(mw[w2] & ia[w2]);
        cnt[a] = (float)c;
    }
    #pragma unroll
    for(int a=0;a<NATOMS;a++){
        cnt[a] += __shfl_xor(cnt[a],1,64);
        cnt[a] += __shfl_xor(cnt[a],2,64);
    }
    float deg = (float)degi;
    deg += __shfl_xor(deg,1,64);
    deg += __shfl_xor(deg,2,64);

    {
        float inv = 1.0f / fmaxf(deg, 1.0f);
        int oid = sid[tile*64 + node];
        int d0 = p*32;
        float vv[32];
        #pragma unroll
        for(int d=0;d<32;d++) vv[d]=0.f;
        #pragma unroll
        for(int a=0;a<NATOMS;a++){
            float ca = cnt[a];
            const float* ea = &emb[a*128 + d0];
            #pragma unroll
            for(int d=0;d<32;d+=4){
                float4 e = *(const float4*)&ea[d];
                vv[d]+=ca*e.x; vv[d+1]+=ca*e.y; vv[d+2]+=ca*e.z; vv[d+3]+=ca*e.w;
            }
        }
        const float* eo = &emb[oid*128 + d0];
        unsigned short* dst = &v_bf[node*136 + d0];
        #pragma unroll
        for(int d=0;d<32;d+=4){
            float4 e = *(const float4*)&eo[d];
            ushort4 o;
            o.x = f2b(e.x + vv[d]*inv);
            o.y = f2b(e.y + vv[d+1]*inv);
            o.z = f2b(e.z + vv[d+2]*inv);
            o.w = f2b(e.w + vv[d+3]*inv);
            *(ushort4*)&dst[d] = o;
        }
    }
    __syncthreads();

    f32x4 acc[2][4];
    #pragma unroll
    for(int i=0;i<2;i++)
        #pragma unroll
        for(int j=0;j<4;j++) acc[i][j] = (f32x4){0.f,0.f,0.f,0.f};
    for(int k0=0;k0<128;k0+=32){
        #pragma unroll
        for(int i=0;i<4;i++){
            int id = tid + i*256; int plane = id>>9, cid = id&511;
            int r = cid>>2, c = cid&3;
            *(bf16x8*)((plane? sBl : sBh) + r*40 + c*8) = wbm[i];
        }
        __syncthreads();
        if(k0 < 96){
            #pragma unroll
            for(int i=0;i<4;i++){ int id=tid+i*256; int plane=id>>9,cid=id&511;
                int r=cid>>2,c=cid&3;
                wbm[i] = *(const bf16x8*)((plane? wmtl:wmth)
                          + (size_t)r*128 + k0+32 + c*8); }
        }
        bf16x8 av[2];
        #pragma unroll
        for(int tm=0;tm<2;tm++)
            av[tm] = *(const bf16x8*)&v_bf[(m0w+tm*16+ln)*136 + k0 + quad*8];
        #pragma unroll
        for(int tn=0;tn<4;tn++){
            bf16x8 bh = *(const bf16x8*)&sBh[(n0w+tn*16+ln)*40 + quad*8];
            bf16x8 bl = *(const bf16x8*)&sBl[(n0w+tn*16+ln)*40 + quad*8];
            #pragma unroll
            for(int tm=0;tm<2;tm++){
                acc[tm][tn] = __builtin_amdgcn_mfma_f32_16x16x32_bf16(av[tm], bl, acc[tm][tn], 0,0,0);
                acc[tm][tn] = __builtin_amdgcn_mfma_f32_16x16x32_bf16(av[tm], bh, acc[tm][tn], 0,0,0);
            }
        }
        __syncthreads();
    }
    bf16x8 wa[4];
    #pragma unroll
    for(int i=0;i<4;i++){ int id=tid+i*256; int plane=id>>9,cid=id&511;
        int r=cid>>2,c=cid&3;
        wa[i] = *(const bf16x8*)((plane? a1tl:a1th) + (size_t)r*128 + c*8); }
    #pragma unroll
    for(int tn=0;tn<4;tn++){
        int col = n0w + tn*16 + ln;
        float bias = s_bm[col];
        #pragma unroll
        for(int tm=0;tm<2;tm++){
            int mb2 = m0w + tm*16 + quad*4;
            #pragma unroll
            for(int r=0;r<4;r++){
                float hv = gelu_f(acc[tm][tn][r] + bias);
                out_z[(size_t)(row0+mb2+r)*128 + col] = hv;
                houts[(mb2+r)*136 + col] = f2b(hv);
            }
        }
    }
    __syncthreads();

    {
        float d0=0.f, d1=0.f, d2=0.f;
        int kb = p*32;
        #pragma unroll
        for(int k=0;k<32;k+=4){
            ushort4 hv = *(const ushort4*)&houts[node*136 + kb + k];
            float h0=b2f(hv.x),h1=b2f(hv.y),h2=b2f(hv.z),h3=b2f(hv.w);
            const float* wc = &s_wc[(kb+k)*3];
            d0 += h0*wc[0]+h1*wc[3]+h2*wc[6]+h3*wc[9];
            d1 += h0*wc[1]+h1*wc[4]+h2*wc[7]+h3*wc[10];
            d2 += h0*wc[2]+h1*wc[5]+h2*wc[8]+h3*wc[11];
        }
        d0 += __shfl_xor(d0,1,64); d0 += __shfl_xor(d0,2,64);
        d1 += __shfl_xor(d1,1,64); d1 += __shfl_xor(d1,2,64);
        d2 += __shfl_xor(d2,1,64); d2 += __shfl_xor(d2,2,64);
        if(p==0){
            size_t o = (size_t)(row0+node)*3;
            out_co[o+0] = coords[o+0] + tanhf(d0);
            out_co[o+1] = coords[o+1] + tanhf(d1);
            out_co[o+2] = coords[o+2] + tanhf(d2);
        }
    }

    f32x4 acc2[2][4];
    #pragma unroll
    for(int i=0;i<2;i++)
        #pragma unroll
        for(int j=0;j<4;j++) acc2[i][j] = (f32x4){0.f,0.f,0.f,0.f};
    for(int k0=0;k0<128;k0+=32){
        __syncthreads();
        #pragma unroll
        for(int i=0;i<4;i++){
            int id = tid + i*256; int plane = id>>9, cid = id&511;
            int r = cid>>2, c = cid&3;
            *(bf16x8*)((plane? sBl : sBh) + r*40 + c*8) = wa[i];
        }
        __syncthreads();
        if(k0 < 96){
            #pragma unroll
            for(int i=0;i<4;i++){ int id=tid+i*256; int plane=id>>9,cid=id&511;
                int r=cid>>2,c=cid&3;
                wa[i] = *(const bf16x8*)((plane? a1tl:a1th)
                          + (size_t)r*128 + k0+32 + c*8); }
        }
        bf16x8 ah[2];
        #pragma unroll
        for(int tm=0;tm<2;tm++)
            ah[tm] = *(const bf16x8*)&houts[(m0w+tm*16+ln)*136 + k0 + quad*8];
        #pragma unroll
        for(int tn=0;tn<4;tn++){
            bf16x8 bh = *(const bf16x8*)&sBh[(n0w+tn*16+ln)*40 + quad*8];
            bf16x8 bl = *(const bf16x8*)&sBl[(n0w+tn*16+ln)*40 + quad*8];
            #pragma unroll
            for(int tm=0;tm<2;tm++){
                acc2[tm][tn] = __builtin_amdgcn_mfma_f32_16x16x32_bf16(ah[tm], bl, acc2[tm][tn], 0,0,0);
                acc2[tm][tn] = __builtin_amdgcn_mfma_f32_16x16x32_bf16(ah[tm], bh, acc2[tm][tn], 0,0,0);
            }
        }
    }
    __syncthreads();
    unsigned short* t1s = houts;
    #pragma unroll
    for(int tn=0;tn<4;tn++){
        int col = n0w + tn*16 + ln;
        if(col < 104){
            float bias = s_a1[col];
            #pragma unroll
            for(int tm=0;tm<2;tm++){
                int mb2 = m0w + tm*16 + quad*4;
                #pragma unroll
                for(int r=0;r<4;r++)
                    t1s[(mb2+r)*104 + col] = f2b(gelu_f(acc2[tm][tn][r] + bias));
            }
        }
    }
    __syncthreads();

    {
        int g0 = (p<2) ? p*7 : 14+(p-2)*6;
        int gcount = (p<2) ? 7 : 6;
        float s[6] = {0.f,0.f,0.f,0.f,0.f,0.f};
        for(int gg=0; gg<gcount; gg++){
            int kb = (g0+gg)*4;
            ushort4 tv = *(const ushort4*)&t1s[node*104 + kb];
            float u0=b2f(tv.x), u1=b2f(tv.y), u2=b2f(tv.z), u3=b2f(tv.w);
            #pragma unroll
            for(int j=0;j<6;j++)
                s[j] += u0*s_A2[kb*6+j] + u1*s_A2[(kb+1)*6+j]
                      + u2*s_A2[(kb+2)*6+j] + u3*s_A2[(kb+3)*6+j];
        }
        #pragma unroll
        for(int j=0;j<6;j++){ s[j]+=__shfl_xor(s[j],1,64); s[j]+=__shfl_xor(s[j],2,64); }
        if(p<2){
            size_t o = (size_t)(row0+node)*6 + p*3;
            #pragma unroll
            for(int jj=0;jj<3;jj++){
                int j = p*3+jj;
                float t2v = gelu_f(s[j] + s_a2[j]);
                float uu = tanhf(s_dyt[0]*t2v)*s_dyt[1+j] + s_dyt[8+j];
                out_ang[o+jj] = tanhf(uu);
            }
        }
    }
}

// ===========================================================================
// COOPERATIVE PATH: one kernel, grid 512, LDS pool 61440 B (<= 64 KB)
// ===========================================================================

struct KParams {
    const float *x, *coords;
    const int   *ei;
    const float *gamma, *beta, *W1, *b1, *W2, *b2, *W3, *b3;
    const float *embed, *W_msg, *b_msg, *w_coor, *A1, *a1v, *A2, *a2v;
    const float *dalpha, *dw, *db;
    float    *stats;
    unsigned *ecnt, *earena;
    short *w1th,*w1tl,*w2th,*w2tl,*wmth,*wmtl,*a1th,*a1tl;
    int   *ids;
    float *out_ang, *out_z, *out_co;
};

__global__ __launch_bounds__(256) void fused_k(KParams P)
{
    __shared__ __align__(16) unsigned char pool[61440];
    cg::grid_group grid = cg::this_grid();
    int tid = threadIdx.x, bx = blockIdx.x;

    // ============================ PHASE P ===================================
    {
        int r0 = bx*64;
        const float* p = P.x + (size_t)r0*INC + tid;
        float s = 0.f, s2 = 0.f;
        #pragma unroll 8
        for(int r=0;r<64;r++){ float v = p[(size_t)r*INC]; s += v; s2 += v*v; }
        atomicAdd(&P.stats[tid], s);
        atomicAdd(&P.stats[INC+tid], s2);

        if((bx&15)==0){
            float* st = (float*)pool;                // [64][65] = 16640 B
            int t = bx>>4;
            const float* src; short *dh, *dl;
            int k0, n0, lds, ldd, nmax;
            if(t < 16){      src=P.W1; dh=P.w1th; dl=P.w1tl; lds=256; ldd=256; nmax=256;
                             k0=(t>>2)*64;      n0=(t&3)*64; }
            else if(t < 24){ int u=t-16; src=P.W2; dh=P.w2th; dl=P.w2tl; lds=128; ldd=256; nmax=128;
                             k0=(u>>1)*64;      n0=(u&1)*64; }
            else if(t < 28){ int u=t-24; src=P.W_msg; dh=P.wmth; dl=P.wmtl; lds=128; ldd=128; nmax=128;
                             k0=(u>>1)*64;      n0=(u&1)*64; }
            else {           int u=t-28; src=P.A1; dh=P.a1th; dl=P.a1tl; lds=100; ldd=128; nmax=100;
                             k0=(u>>1)*64;      n0=(u&1)*64; }
            #pragma unroll
            for(int i=0;i<16;i++){
                int idx = tid + i*256; int r = idx>>6, c = idx&63;
                float v = (n0+c < nmax) ? src[(size_t)(k0+r)*lds + n0+c] : 0.f;
                st[r*65+c] = v;
            }
            __syncthreads();
            #pragma unroll
            for(int i=0;i<16;i++){
                int idx = tid + i*256; int rr = idx>>6, cc = idx&63;
                unsigned short hi, lo;
                splitf(st[cc*65+rr], hi, lo);
                size_t o = (size_t)(n0+rr)*ldd + k0+cc;
                dh[o] = (short)hi; dl[o] = (short)lo;
            }
        }
    }
    __threadfence();
    grid.sync();
    __threadfence();

    // ============================ PHASE B ===================================
    {
        float* sc = (float*)pool;                    // [256]
        float* sh = (float*)(pool + 1024);           // [256]
        unsigned char* smem = pool + 2048;           // 51200 B -> ends 53248
        short* sAh = (short*)smem;
        short* sAl = sAh + 64*40;
        short* sBh = (short*)(smem + 10240);
        short* sBl = sBh + 256*40;
        float* h2s = (float*)(smem + 10240);
        float* lgs = (float*)(smem + 44032);
        float* w3s = (float*)smem;

        {
            float mu  = P.stats[tid]*(1.0f/NT);
            float var = P.stats[256+tid]*(1.0f/NT) - mu*mu;
            float s = P.gamma[tid]/sqrtf(var + 1e-5f);
            sc[tid] = s; sh[tid] = P.beta[tid] - mu*s;
        }
        int row0 = bx*64;
        int lane = tid&63, w = tid>>6;
        int ln = lane&15, quad = lane>>4;
        int m0w = (w&1)*32, nb1 = (w>>1)*128, nb2 = (w>>1)*64;

        f32x4 acc[2][8];
        #pragma unroll
        for(int i=0;i<2;i++)
            #pragma unroll
            for(int j=0;j<8;j++) acc[i][j] = (f32x4){0.f,0.f,0.f,0.f};
        float bias1[8];
        #pragma unroll
        for(int tn=0;tn<8;tn++) bias1[tn] = P.b1[nb1 + tn*16 + ln];

        float4 xa[2][2]; bf16x8 wb[2][8];
        #pragma unroll
        for(int t=0;t<2;t++){
            #pragma unroll
            for(int i=0;i<2;i++){ int id=tid+i*256; int r=id>>3,kq=(id&7)*4;
                xa[t][i] = *(const float4*)&P.x[(size_t)(row0+r)*256 + t*32 + kq]; }
            #pragma unroll
            for(int i=0;i<8;i++){ int id=tid+i*256; int plane=id>>10,cid=id&1023;
                int r=cid>>2,c=cid&3;
                wb[t][i] = *(const bf16x8*)((plane? P.w1tl:P.w1th) + (size_t)r*256 + t*32 + c*8); }
        }
        __syncthreads();
        for(int k0=0;k0<256;k0+=32){
            int cur = (k0>>5)&1;
            #pragma unroll
            for(int i=0;i<2;i++){
                int id = tid + i*256; int r = id>>3, kq = (id&7)*4;
                int k = k0+kq;
                float v0 = xa[cur][i].x*sc[k]+sh[k],     v1 = xa[cur][i].y*sc[k+1]+sh[k+1];
                float v2 = xa[cur][i].z*sc[k+2]+sh[k+2], v3 = xa[cur][i].w*sc[k+3]+sh[k+3];
                ushort4 hi, lo;
                splitf(v0,hi.x,lo.x); splitf(v1,hi.y,lo.y);
                splitf(v2,hi.z,lo.z); splitf(v3,hi.w,lo.w);
                *(ushort4*)&sAh[r*40+kq] = hi;
                *(ushort4*)&sAl[r*40+kq] = lo;
            }
            #pragma unroll
            for(int i=0;i<8;i++){
                int id = tid + i*256; int plane = id>>10, cid = id&1023;
                int r = cid>>2, c = cid&3;
                *(bf16x8*)((plane? sBl : sBh) + r*40 + c*8) = wb[cur][i];
            }
            __syncthreads();
            if(k0 < 192){
                #pragma unroll
                for(int i=0;i<2;i++){ int id=tid+i*256; int r=id>>3,kq=(id&7)*4;
                    xa[cur][i] = *(const float4*)&P.x[(size_t)(row0+r)*256 + k0+64+kq]; }
                #pragma unroll
                for(int i=0;i<8;i++){ int id=tid+i*256; int plane=id>>10,cid=id&1023;
                    int r=cid>>2,c=cid&3;
                    wb[cur][i] = *(const bf16x8*)((plane? P.w1tl:P.w1th) + (size_t)r*256 + k0+64 + c*8); }
            }
            bf16x8 ah[2], al[2];
            #pragma unroll
            for(int tm=0;tm<2;tm++){
                ah[tm] = *(const bf16x8*)&sAh[(m0w+tm*16+ln)*40 + quad*8];
                al[tm] = *(const bf16x8*)&sAl[(m0w+tm*16+ln)*40 + quad*8];
            }
            #pragma unroll
            for(int tn=0;tn<8;tn++){
                bf16x8 bh = *(const bf16x8*)&sBh[(nb1+tn*16+ln)*40 + quad*8];
                bf16x8 bl = *(const bf16x8*)&sBl[(nb1+tn*16+ln)*40 + quad*8];
                #pragma unroll
                for(int tm=0;tm<2;tm++){
                    acc[tm][tn] = __builtin_amdgcn_mfma_f32_16x16x32_bf16(al[tm], bh, acc[tm][tn], 0,0,0);
                    acc[tm][tn] = __builtin_amdgcn_mfma_f32_16x16x32_bf16(ah[tm], bl, acc[tm][tn], 0,0,0);
                    acc[tm][tn] = __builtin_amdgcn_mfma_f32_16x16x32_bf16(ah[tm], bh, acc[tm][tn], 0,0,0);
                }
            }
            __syncthreads();
        }

        f32x4 acc2[2][4];
        #pragma unroll
        for(int i=0;i<2;i++)
            #pragma unroll
            for(int j=0;j<4;j++) acc2[i][j] = (f32x4){0.f,0.f,0.f,0.f};
        bf16x8 wb2[4];
        #pragma unroll
        for(int i=0;i<4;i++){ int id=tid+i*256; int plane=id>>9,cid=id&511;
            int r=cid>>2,c=cid&3;
            wb2[i] = *(const bf16x8*)((plane? P.w2tl:P.w2th) + (size_t)r*256 + c*8); }
        #pragma unroll
        for(int cc=0;cc<8;cc++){
            if((w>>1) == (cc>>2)){
                int clp = cc&3;
                #pragma unroll
                for(int t=0;t<2;t++){
                    int tn = 2*clp + t;
                    #pragma unroll
                    for(int tm=0;tm<2;tm++){
                        #pragma unroll
                        for(int r=0;r<4;r++){
                            int row = m0w + tm*16 + quad*4 + r;
                            float hv = gelu_f(acc[tm][tn][r] + bias1[tn]);
                            unsigned short hi, lo;
                            splitf(hv, hi, lo);
                            sAh[row*40 + t*16 + ln] = (short)hi;
                            sAl[row*40 + t*16 + ln] = (short)lo;
                        }
                    }
                }
            }
            #pragma unroll
            for(int i=0;i<4;i++){
                int id = tid + i*256; int plane = id>>9, cid = id&511;
                int r = cid>>2, c = cid&3;
                *(bf16x8*)((plane? sBl : sBh) + r*40 + c*8) = wb2[i];
            }
            __syncthreads();
            if(cc < 7){
                #pragma unroll
                for(int i=0;i<4;i++){ int id=tid+i*256; int plane=id>>9,cid=id&511;
                    int r=cid>>2,c=cid&3;
                    wb2[i] = *(const bf16x8*)((plane? P.w2tl:P.w2th)
                              + (size_t)r*256 + (cc+1)*32 + c*8); }
            }
            bf16x8 ah[2], al[2];
            #pragma unroll
            for(int tm=0;tm<2;tm++){
                ah[tm] = *(const bf16x8*)&sAh[(m0w+tm*16+ln)*40 + quad*8];
                al[tm] = *(const bf16x8*)&sAl[(m0w+tm*16+ln)*40 + quad*8];
            }
            #pragma unroll
            for(int tn=0;tn<4;tn++){
                bf16x8 bh = *(const bf16x8*)&sBh[(nb2+tn*16+ln)*40 + quad*8];
                bf16x8 bl = *(const bf16x8*)&sBl[(nb2+tn*16+ln)*40 + quad*8];
                #pragma unroll
                for(int tm=0;tm<2;tm++){
                    acc2[tm][tn] = __builtin_amdgcn_mfma_f32_16x16x32_bf16(al[tm], bh, acc2[tm][tn], 0,0,0);
                    acc2[tm][tn] = __builtin_amdgcn_mfma_f32_16x16x32_bf16(ah[tm], bl, acc2[tm][tn], 0,0,0);
                    acc2[tm][tn] = __builtin_amdgcn_mfma_f32_16x16x32_bf16(ah[tm], bh, acc2[tm][tn], 0,0,0);
                }
            }
            __syncthreads();
        }

        #pragma unroll
        for(int tn=0;tn<4;tn++){
            int col = nb2 + tn*16 + ln;
            float bias = P.b2[col];
            #pragma unroll
            for(int tm=0;tm<2;tm++){
                int rb = m0w + tm*16 + quad*4;
                #pragma unroll
                for(int r=0;r<4;r++)
                    h2s[(rb+r)*132 + col] = gelu_f(acc2[tm][tn][r] + bias);
            }
        }
        for(int l=tid;l<2560;l+=256) w3s[l] = P.W3[l];
        __syncthreads();
        {
            int n = tid>>2, q = tid&3;
            float lg[5] = {};
            #pragma unroll 4
            for(int k=0;k<128;k++){
                float h = h2s[n*132+k];
                #pragma unroll
                for(int a=0;a<5;a++) lg[a] += h*w3s[k*20 + q*5 + a];
            }
            #pragma unroll
            for(int a=0;a<5;a++) lgs[n*20 + q*5 + a] = lg[a] + P.b3[q*5+a];
        }
        __syncthreads();
        if(tid<64){
            float best = lgs[tid*20]; int bi = 0;
            #pragma unroll
            for(int a=1;a<20;a++){ float v2 = lgs[tid*20+a]; if(v2>best){best=v2;bi=a;} }
            P.ids[row0+tid] = bi;
        }

        if(bx < 256){
            __syncthreads();
            unsigned* lcnt  = (unsigned*)sAh;
            unsigned* gbase = ((unsigned*)sAh) + 512;
            for(int l=tid; l<512; l+=256) lcnt[l] = 0;
            __syncthreads();
            int ebase = bx * 4096;
            #pragma unroll 4
            for(int i=0;i<16;i++){
                int e = ebase + i*256 + tid;
                int s = P.ei[e], d = P.ei[Ee+e];
                if((s>>11)==(d>>11)) atomicAdd(&lcnt[s>>6], 1u);
            }
            __syncthreads();
            for(int l=tid; l<512; l+=256){
                unsigned c = lcnt[l];
                gbase[l] = c ? atomicAdd(&P.ecnt[l], c) : 0u;
                lcnt[l] = 0;
            }
            __syncthreads();
            #pragma unroll 4
            for(int i=0;i<16;i++){
                int e = ebase + i*256 + tid;
                int s = P.ei[e], d = P.ei[Ee+e];
                if((s>>11)==(d>>11)){
                    int bin = s>>6;
                    unsigned r = atomicAdd(&lcnt[bin], 1u);
                    unsigned pos = gbase[bin] + r;
                    if(pos < BINCAP)
                        P.earena[(size_t)bin*BINCAP + pos] =
                            ((unsigned)(s&63)<<11) | (unsigned)(d&2047);
                }
            }
        }
    }
    __threadfence();
    grid.sync();
    __threadfence();

    // ============================ PHASE C ===================================
    {
        unsigned short* v_bf  = (unsigned short*)pool;            // 17408 B
        unsigned short* houts = (unsigned short*)(pool + 17408);  // 17408 B
        unsigned char*  arena = pool + 34816;                     // 26624 B
        unsigned* lmask = (unsigned*)arena;                       // 16384 B
        float*    emb   = (float*)(arena + 16384);                // 10240 B
        unsigned* ind   = (unsigned*)(pool + 17408);              // in houts (dead)
        unsigned char* sid = pool + 17408 + 5120;                 // in houts (dead)
        short* sBh = (short*)arena;                               // 10240 B
        short* sBl = (short*)(arena + 10240);                     // 10240 B
        float* s_bm  = (float*)(arena + 20480);                   // late constants
        float* s_wc  = (float*)(arena + 20992);
        float* s_A2  = (float*)(arena + 22528);
        float* s_a1  = (float*)(arena + 25024);
        float* s_dyt = (float*)(arena + 25440);
        float* s_a2  = (float*)(arena + 25504);

        int bin = bx;
        int row0 = bin*64;
        int g = bx>>5, tile = bx&31;
        int lane = tid&63, w = tid>>6;
        int ln = lane&15, quad = lane>>4;
        int m0w = (w&1)*32, n0w = (w>>1)*64;

        int nbin = min((int)P.ecnt[bin], BINCAP);
        for(int l=tid;l<NATOMS*128;l+=256) emb[l] = P.embed[l];
        #pragma unroll
        for(int i=0;i<8;i++){ int j = tid + i*256; sid[j] = (unsigned char)P.ids[g*Nn + j]; }
        #pragma unroll
        for(int i=0;i<16;i++) lmask[tid + i*256] = 0;
        __syncthreads();

        unsigned ew[12]; int ne = 0;
        #pragma unroll
        for(int j=0;j<12;j++){
            int i = tid + j*256;
            if(i < nbin){ ew[j] = P.earena[(size_t)bin*BINCAP + i]; ne = j+1; }
        }
        for(int wp=w; wp<32; wp+=4){
            int a = sid[wp*64 + lane];
            #pragma unroll
            for(int atom=0; atom<NATOMS; atom++){
                unsigned long long bm = __ballot(a==atom);
                if(lane<2) ind[atom*64 + wp*2 + lane] = (unsigned)(bm >> (32*lane));
            }
        }
        for(int j=0;j<ne;j++){
            unsigned wv = ew[j];
            int sl = wv>>11, dl = wv & 2047;
            atomicOr(&lmask[sl*64 + (dl>>5)], 1u<<(dl&31));
        }
        __syncthreads();

        bf16x8 wbm[4];
        #pragma unroll
        for(int i=0;i<4;i++){ int id=tid+i*256; int plane=id>>9,cid=id&511;
            int r=cid>>2,c=cid&3;
            wbm[i] = *(const bf16x8*)((plane? P.wmtl:P.wmth) + (size_t)r*128 + c*8); }
        int node = tid>>2, p = tid&3;
        unsigned mw[16];
        {
            const unsigned* mrow = &lmask[node*64 + p*16];
            *(uint4*)&mw[0]  = *(const uint4*)&mrow[0];
            *(uint4*)&mw[4]  = *(const uint4*)&mrow[4];
            *(uint4*)&mw[8]  = *(const uint4*)&mrow[8];
            *(uint4*)&mw[12] = *(const uint4*)&mrow[12];
        }
        int degi = 0;
        #pragma unroll
        for(int w2=0;w2<16;w2++) degi += __popc(mw[w2]);
        float cnt[NATOMS];
        #pragma unroll
        for(int a=0;a<NATOMS;a++){
            int c = 0;
            const unsigned* ia = &ind[a*64 + p*16];
            #pragma unroll
            for(int w2=0;w2<16;w2++) c += __popc(mw[w2] & ia[w2]);
            cnt[a] = (float)c;
        }
        #pragma unroll
        for(int a=0;a<NATOMS;a++){
            cnt[a] += __shfl_xor(cnt[a],1,64);
            cnt[a] += __shfl_xor(cnt[a],2,64);
        }
        float deg = (float)degi;
        deg += __shfl_xor(deg,1,64);
        deg += __shfl_xor(deg,2,64);

        {
            float inv = 1.0f / fmaxf(deg, 1.0f);
            int oid = sid[tile*64 + node];
            int d0 = p*32;
            float vv[32];
            #pragma unroll
            for(int d=0;d<32;d++) vv[d]=0.f;
            #pragma unroll
            for(int a=0;a<NATOMS;a++){
                float ca = cnt[a];
                const float* ea = &emb[a*128 + d0];
                #pragma unroll
                for(int d=0;d<32;d+=4){
                    float4 e = *(const float4*)&ea[d];
                    vv[d]+=ca*e.x; vv[d+1]+=ca*e.y; vv[d+2]+=ca*e.z; vv[d+3]+=ca*e.w;
                }
            }
            const float* eo = &emb[oid*128 + d0];
            unsigned short* dst = &v_bf[node*136 + d0];
            #pragma unroll
            for(int d=0;d<32;d+=4){
                float4 e = *(const float4*)&eo[d];
                ushort4 o;
                o.x = f2b(e.x + vv[d]*inv);
                o.y = f2b(e.y + vv[d+1]*inv);
                o.z = f2b(e.z + vv[d+2]*inv);
                o.w = f2b(e.w + vv[d+3]*inv);
                *(ushort4*)&dst[d] = o;
            }
        }
        __syncthreads();     // v complete; lmask/ind/sid/emb all dead now

        // late constant loads into dead region (read only after loop barriers)
        if(tid<128) s_bm[tid] = P.b_msg[tid];
        if(tid<104) s_a1[tid] = (tid<ENCH) ? P.a1v[tid] : 0.f;
        for(int l=tid;l<384;l+=256) s_wc[l] = P.w_coor[l];
        for(int l=tid;l<624;l+=256) s_A2[l] = (l<600) ? P.A2[l] : 0.f;
        if(tid==0)  s_dyt[0] = P.dalpha[0];
        if(tid<6){ s_dyt[1+tid] = P.dw[tid]; s_dyt[8+tid] = P.db[tid]; }
        if(tid<8)  s_a2[tid] = (tid<6) ? P.a2v[tid] : 0.f;

        f32x4 acc[2][4];
        #pragma unroll
        for(int i=0;i<2;i++)
            #pragma unroll
            for(int j=0;j<4;j++) acc[i][j] = (f32x4){0.f,0.f,0.f,0.f};
        for(int k0=0;k0<128;k0+=32){
            #pragma unroll
            for(int i=0;i<4;i++){
                int id = tid + i*256; int plane = id>>9, cid = id&511;
                int r = cid>>2, c = cid&3;
                *(bf16x8*)((plane? sBl : sBh) + r*40 + c*8) = wbm[i];
            }
            __syncthreads();
            if(k0 < 96){
                #pragma unroll
                for(int i=0;i<4;i++){ int id=tid+i*256; int plane=id>>9,cid=id&511;
                    int r=cid>>2,c=cid&3;
                    wbm[i] = *(const bf16x8*)((plane? P.wmtl:P.wmth)
                              + (size_t)r*128 + k0+32 + c*8); }
            }
            bf16x8 av[2];
            #pragma unroll
            for(int tm=0;tm<2;tm++)
                av[tm] = *(const bf16x8*)&v_bf[(m0w+tm*16+ln)*136 + k0 + quad*8];
            #pragma unroll
            for(int tn=0;tn<4;tn++){
                bf16x8 bh = *(const bf16x8*)&sBh[(n0w+tn*16+ln)*40 + quad*8];
                bf16x8 bl = *(const bf16x8*)&sBl[(n0w+tn*16+ln)*40 + quad*8];
                #pragma unroll
                for(int tm=0;tm<2;tm++){
                    acc[tm][tn] = __builtin_amdgcn_mfma_f32_16x16x32_bf16(av[tm], bl, acc[tm][tn], 0,0,0);
                    acc[tm][tn] = __builtin_amdgcn_mfma_f32_16x16x32_bf16(av[tm], bh, acc[tm][tn], 0,0,0);
                }
            }
            __syncthreads();
        }
        bf16x8 wa[4];
        #pragma unroll
        for(int i=0;i<4;i++){ int id=tid+i*256; int plane=id>>9,cid=id&511;
            int r=cid>>2,c=cid&3;
            wa[i] = *(const bf16x8*)((plane? P.a1tl:P.a1th) + (size_t)r*128 + c*8); }
        #pragma unroll
        for(int tn=0;tn<4;tn++){
            int col = n0w + tn*16 + ln;
            float bias = s_bm[col];
            #pragma unroll
            for(int tm=0;tm<2;tm++){
                int mb2 = m0w + tm*16 + quad*4;
                #pragma unroll
                for(int r=0;r<4;r++){
                    float hv = gelu_f(acc[tm][tn][r] + bias);
                    P.out_z[(size_t)(row0+mb2+r)*128 + col] = hv;
                    houts[(mb2+r)*136 + col] = f2b(hv);
                }
            }
        }
        __syncthreads();

        {
            float d0=0.f, d1=0.f, d2=0.f;
            int kb = p*32;
            #pragma unroll
            for(int k=0;k<32;k+=4){
                ushort4 hv = *(const ushort4*)&houts[node*136 + kb + k];
                float h0=b2f(hv.x),h1=b2f(hv.y),h2=b2f(hv.z),h3=b2f(hv.w);
                const float* wc = &s_wc[(kb+k)*3];
                d0 += h0*wc[0]+h1*wc[3]+h2*wc[6]+h3*wc[9];
                d1 += h0*wc[1]+h1*wc[4]+h2*wc[7]+h3*wc[10];
                d2 += h0*wc[2]+h1*wc[5]+h2*wc[8]+h3*wc[11];
            }
            d0 += __shfl_xor(d0,1,64); d0 += __shfl_xor(d0,2,64);
            d1 += __shfl_xor(d1,1,64); d1 += __shfl_xor(d1,2,64);
            d2 += __shfl_xor(d2,1,64); d2 += __shfl_xor(d2,2,64);
            if(p==0){
                size_t o = (size_t)(row0+node)*3;
                P.out_co[o+0] = P.coords[o+0] + tanhf(d0);
                P.out_co[o+1] = P.coords[o+1] + tanhf(d1);
                P.out_co[o+2] = P.coords[o+2] + tanhf(d2);
            }
        }

        f32x4 acc2[2][4];
        #pragma unroll
        for(int i=0;i<2;i++)
            #pragma unroll
            for(int j=0;j<4;j++) acc2[i][j] = (f32x4){0.f,0.f,0.f,0.f};
        for(int k0=0;k0<128;k0+=32){
            __syncthreads();
            #pragma unroll
            for(int i=0;i<4;i++){
                int id = tid + i*256; int plane = id>>9, cid = id&511;
                int r = cid>>2, c = cid&3;
                *(bf16x8*)((plane? sBl : sBh) + r*40 + c*8) = wa[i];
            }
            __syncthreads();
            if(k0 < 96){
                #pragma unroll
                for(int i=0;i<4;i++){ int id=tid+i*256; int plane=id>>9,cid=id&511;
                    int r=cid>>2,c=cid&3;
                    wa[i] = *(const bf16x8*)((plane? P.a1tl:P.a1th)
                              + (size_t)r*128 + k0+32 + c*8); }
            }
            bf16x8 ah[2];
            #pragma unroll
            for(int tm=0;tm<2;tm++)
                ah[tm] = *(const bf16x8*)&houts[(m0w+tm*16+ln)*136 + k0 + quad*8];
            #pragma unroll
            for(int tn=0;tn<4;tn++){
                bf16x8 bh = *(const bf16x8*)&sBh[(n0w+tn*16+ln)*40 + quad*8];
                bf16x8 bl = *(const bf16x8*)&sBl[(n0w+tn*16+ln)*40 + quad*8];
                #pragma unroll
                for(int tm=0;tm<2;tm++){
                    acc2[tm][tn] = __builtin_amdgcn_mfma_f32_16x16x32_bf16(ah[tm], bl, acc2[tm][tn], 0,0,0);
                    acc2[tm][tn] = __builtin_amdgcn_mfma_f32_16x16x32_bf16(ah[tm], bh, acc2[tm][tn], 0,0,0);
                }
            }
        }
        __syncthreads();
        unsigned short* t1s = houts;
        #pragma unroll
        for(int tn=0;tn<4;tn++){
            int col = n0w + tn*16 + ln;
            if(col < 104){
                float bias = s_a1[col];
                #pragma unroll
                for(int tm=0;tm<2;tm++){
                    int mb2 = m0w + tm*16 + quad*4;
                    #pragma unroll
                    for(int r=0;r<4;r++)
                        t1s[(mb2+r)*104 + col] = f2b(gelu_f(acc2[tm][tn][r] + bias));
                }
            }
        }
        __syncthreads();

        {
            int g0 = (p<2) ? p*7 : 14+(p-2)*6;
            int gcount = (p<2) ? 7 : 6;
            float s[6] = {0.f,0.f,0.f,0.f,0.f,0.f};
            for(int gg=0; gg<gcount; gg++){
                int kb = (g0+gg)*4;
                ushort4 tv = *(const ushort4*)&t1s[node*104 + kb];
                float u0=b2f(tv.x), u1=b2f(tv.y), u2=b2f(tv.z), u3=b2f(tv.w);
                #pragma unroll
                for(int j=0;j<6;j++)
                    s[j] += u0*s_A2[kb*6+j] + u1*s_A2[(kb+1)*6+j]
                          + u2*s_A2[(kb+2)*6+j] + u3*s_A2[(kb+3)*6+j];
            }
            #pragma unroll
            for(int j=0;j<6;j++){ s[j]+=__shfl_xor(s[j],1,64); s[j]+=__shfl_xor(s[j],2,64); }
            if(p<2){
                size_t o = (size_t)(row0+node)*6 + p*3;
                #pragma unroll
                for(int jj=0;jj<3;jj++){
                    int j = p*3+jj;
                    float t2v = gelu_f(s[j] + s_a2[j]);
                    float uu = tanhf(s_dyt[0]*t2v)*s_dyt[1+j] + s_dyt[8+j];
                    P.out_ang[o+jj] = tanhf(uu);
                }
            }
        }
    }
}

// ---------------------------------------------------------------------------
extern "C" void kernel_launch(void* const* d_in, const int* in_sizes, int n_in,
                              void* d_out, int out_size, void* d_ws, size_t ws_size,
                              hipStream_t stream) {
    char* ws = (char*)d_ws;
    KParams P;
    P.x      = (const float*)d_in[0];
    P.coords = (const float*)d_in[1];
    P.ei     = (const int*)d_in[2];
    P.gamma  = (const float*)d_in[4];
    P.beta   = (const float*)d_in[5];
    P.W1     = (const float*)d_in[6];
    P.b1     = (const float*)d_in[7];
    P.W2     = (const float*)d_in[8];
    P.b2     = (const float*)d_in[9];
    P.W3     = (const float*)d_in[10];
    P.b3     = (const float*)d_in[11];
    P.embed  = (const float*)d_in[12];
    P.W_msg  = (const float*)d_in[13];
    P.b_msg  = (const float*)d_in[14];
    P.w_coor = (const float*)d_in[15];
    P.A1     = (const float*)d_in[16];
    P.a1v    = (const float*)d_in[17];
    P.A2     = (const float*)d_in[18];
    P.a2v    = (const float*)d_in[19];
    P.dalpha = (const float*)d_in[20];
    P.dw     = (const float*)d_in[21];
    P.db     = (const float*)d_in[22];
    P.ids    = (int*)ws;
    P.stats  = (float*)(ws + 131072);
    P.ecnt   = (unsigned*)(ws + 131072 + 2048);
    P.w1th   = (short*)(ws + 262144);
    P.w1tl   = P.w1th + 65536;
    P.w2th   = P.w1tl + 65536;
    P.w2tl   = P.w2th + 32768;
    P.wmth   = P.w2tl + 32768;
    P.wmtl   = P.wmth + 16384;
    P.a1th   = P.wmtl + 16384;
    P.a1tl   = P.a1th + 16384;
    P.earena = (unsigned*)(ws + (1<<20));
    P.out_ang = (float*)d_out;
    P.out_z   = P.out_ang + (size_t)NT*OUTC;
    P.out_co  = P.out_z   + (size_t)NT*DIMd;

    hipMemsetAsync(P.stats, 0, 4096, stream);      // stats + ecnt

    // Side-effect-free, deterministic gate: cooperative only if the runtime
    // guarantees 2 blocks/CU co-residency (512-block grid needs 2 x 256 CUs).
    int occ = 0;
    hipError_t qe = hipOccupancyMaxActiveBlocksPerMultiprocessor(
        &occ, (const void*)fused_k, 256, 0);
    bool coop_ok = (qe == hipSuccess && occ >= 2);
    if(coop_ok){
        void* args[] = { &P };
        hipError_t rc = hipLaunchCooperativeKernel((const void*)fused_k,
            dim3(512), dim3(256), args, 0, stream);
        if(rc == hipSuccess) return;
    }

    // Fallback: known-good R8 three-dispatch pipeline (bit-identical outputs)
    prep0_k<<<288, 256, 0, stream>>>(P.x, P.stats, P.W1, P.W2, P.W_msg, P.A1,
        P.w1th, P.w1tl, P.w2th, P.w2tl, P.wmth, P.wmtl, P.a1th, P.a1tl);
    gemm123_k<<<512, 256, 0, stream>>>(P.x, P.stats, P.gamma, P.beta,
        P.w1th, P.w1tl, P.b1, P.w2th, P.w2tl, P.b2, P.W3, P.b3, P.ids,
        P.ei, P.ecnt, P.earena);
    msg3_k<<<512, 256, 0, stream>>>(P.ids, P.ecnt, P.earena, P.embed,
        P.wmth, P.wmtl, P.b_msg, P.w_coor, P.a1th, P.a1tl, P.a1v, P.A2,
        P.a2v, P.dalpha, P.dw, P.db, P.coords,
        P.out_ang, P.out_z, P.out_co);
}